// Round 19
// baseline (372.123 us; speedup 1.0000x reference)
//
#include <hip/hip_runtime.h>
#include <hip/hip_bf16.h>
#include <cstddef>

#define SP 3136          // 56*56
#define CIN 64
#define COUT 256
#define NB 32
#define NEG_SLOPE 0.01f

typedef __attribute__((ext_vector_type(8))) short short8v;  // 8 bf16 (4 VGPRs)
typedef __attribute__((ext_vector_type(4))) float f32x4;    // MFMA accumulator

__device__ __forceinline__ float bfr(ushort h) {
    union { uint u; float f; } c; c.u = ((uint)h) << 16; return c.f;
}
__device__ __forceinline__ void split_bf(float v, ushort& hi, ushort& lo) {
    __hip_bfloat16 h = __float2bfloat16(v);
    float r = v - __bfloat162float(h);
    __hip_bfloat16 l2 = __float2bfloat16(r);
    hi = *(ushort*)&h; lo = *(ushort*)&l2;
}
__device__ __forceinline__ ushort bf_hi(float v) {
    __hip_bfloat16 h = __float2bfloat16(v);
    return *(ushort*)&h;
}

// XOR swizzle: logical 8-ushort group g of row -> physical ushort offset
#define SWZ(row, g) ((((g) ^ ((row) & 7))) * 8)

// ---------------------------------------------------------------------------
// pack_w: W[co][ci][ky][kx] f32 -> fragment-contiguous planes (unchanged)
// ---------------------------------------------------------------------------
__global__ __launch_bounds__(256)
void pack_w(const float* __restrict__ W, ushort* __restrict__ wh, ushort* __restrict__ wl)
{
    const int id = blockIdx.x * 256 + threadIdx.x;   // 147456 = 9*256*64
    const int ci = id & 63, co = (id >> 6) & 255, tap = id >> 14;
    float v = W[(size_t)(co * 64 + ci) * 9 + tap];
    ushort hi, lo; split_bf(v, hi, lo);
    const int ks = ci >> 5, cig = (ci >> 3) & 3, ce = ci & 7;
    const size_t o = (((size_t)(tap * 2 + ks) * 4 + cig) * 256 + co) * 8 + ce;
    wh[o] = hi; wl[o] = lo;
}

// ---------------------------------------------------------------------------
// conv_fused v4 (unchanged from round 18 — pipelined A-gather, 153 µs,
// MfmaUtil 52%, VGPR 108, no spill)
// ---------------------------------------------------------------------------
__global__ __launch_bounds__(256, 2)
void conv_fused(const float* __restrict__ xsrc, const float* __restrict__ nsrc,
                const ushort* __restrict__ Wf_hi, const ushort* __restrict__ Wf_lo,
                const float* __restrict__ bias,
                ushort* __restrict__ h1h, ushort* __restrict__ h1l,
                ushort* __restrict__ hnh, ushort* __restrict__ hnl)
{
    __shared__ __align__(16) ushort Bh[4 * 58 * 64]; // 29 KB
    __shared__ __align__(16) ushort Bl[4 * 58 * 64]; // 29 KB
    const int tid = threadIdx.x;
    const int w = tid >> 6, l = tid & 63;
    const int rp  = blockIdx.x;                      // 0..27
    const int img = blockIdx.y;                      // 0..63
    const int imgb = img & (NB - 1);
    const int y0 = rp * 2, p0 = rp * 112;
    const int co_w = w * 64;                         // wave's co base (4x64=256)

    const float* __restrict__ src = (img < NB ? xsrc : nsrc) + (size_t)imgb * CIN * SP;
    ushort* __restrict__ dh = (img < NB ? h1h : hnh) + (size_t)imgb * COUT * SP;
    ushort* __restrict__ dl = (img < NB ? h1l : hnl) + (size_t)imgb * COUT * SP;

    int sy[4];
    #pragma unroll
    for (int j = 0; j < 4; ++j) sy[j] = (y0 + 55 + j) % 56;   // padded row y0+j

    // ---- stage B once: raw f32 -> split bf16 -> LDS [j][x][ci] swizzled ----
    {
        const int ci = tid >> 2, seg = tid & 3;      // 64 ci x 4 col-segments(14)
        #pragma unroll
        for (int j = 0; j < 4; ++j) {
            const float* r = src + (size_t)ci * SP + sy[j] * 56 + seg * 14;
            #pragma unroll
            for (int c = 0; c < 14; ++c) {
                float v = r[c];
                ushort hi, lo; split_bf(v, hi, lo);
                const int x = seg * 14 + c + 1;      // padded col = orig col + 1
                const int idx = ((j * 58 + x) << 6) + (((ci >> 3) ^ (x & 7)) << 3) + (ci & 7);
                Bh[idx] = hi; Bl[idx] = lo;
            }
        }
        // wrap columns: x=0 <- orig col 55, x=57 <- orig col 0 (512 slots, 2/thr)
        #pragma unroll
        for (int s = 0; s < 2; ++s) {
            const int slot = tid * 2 + s;
            const int j2 = slot >> 7, ci2 = (slot >> 1) & 63, side = slot & 1;
            const float* r2 = src + (size_t)ci2 * SP + sy[j2] * 56;
            const float v = side ? r2[0] : r2[55];
            const int x = side ? 57 : 0;
            ushort hi, lo; split_bf(v, hi, lo);
            const int idx = ((j2 * 58 + x) << 6) + (((ci2 >> 3) ^ (x & 7)) << 3) + (ci2 & 7);
            Bh[idx] = hi; Bl[idx] = lo;
        }
    }
    __syncthreads();                                 // the ONLY barrier

    f32x4 acc[4][7];
    {
        const int rr = (l >> 4) * 4;
        #pragma unroll
        for (int m = 0; m < 4; ++m) {
            const int cb = co_w + 16 * m + rr;
            f32x4 bv = { bias[cb], bias[cb + 1], bias[cb + 2], bias[cb + 3] };
            #pragma unroll
            for (int nf = 0; nf < 7; ++nf) acc[m][nf] = bv;
        }
    }

    // per-nf spatial decomposition (lane-dependent, tap-invariant)
    int b58[7], bx[7];
    #pragma unroll
    for (int nf = 0; nf < 7; ++nf) {
        const int sp = nf * 16 + (l & 15);           // 0..111
        const int ry = (sp >= 56) ? 1 : 0;
        const int xx = sp - ry * 56;
        b58[nf] = ry * 58 + xx;
        bx[nf]  = xx;
    }

    // A-fragment base offsets (iter stride = 4*256*8 = 8192 ushorts)
    size_t aoff[4];
    #pragma unroll
    for (int m = 0; m < 4; ++m)
        aoff[m] = ((size_t)(l >> 4) * 256 + co_w + 16 * m + (l & 15)) * 8;

    short8v cah[4], cal[4];                          // current A fragments
    #pragma unroll
    for (int m = 0; m < 4; ++m) {
        cah[m] = *(const short8v*)(Wf_hi + aoff[m]);
        cal[m] = *(const short8v*)(Wf_lo + aoff[m]);
    }

    for (int it = 0; it < 18; ++it) {                // it = tap*2 + ks
        const int tap = it >> 1, ks = it & 1;
        const int dy = tap / 3, dx = tap - dy * 3;
        const int toff = dy * 58 + dx;
        const int grp = ks * 4 + (l >> 4);

        short8v nah[4], nal[4];                      // prefetch next iter's A
        {
            const size_t po = (size_t)(it < 17 ? it + 1 : it) * 8192;
            #pragma unroll
            for (int m = 0; m < 4; ++m) {
                nah[m] = *(const short8v*)(Wf_hi + aoff[m] + po);
                nal[m] = *(const short8v*)(Wf_lo + aoff[m] + po);
            }
        }

        #pragma unroll
        for (int nf = 0; nf < 7; ++nf) {
            const int x  = bx[nf] + dx;
            const int bi = ((b58[nf] + toff) << 6) + ((grp ^ (x & 7)) << 3);
            short8v bh  = *(const short8v*)&Bh[bi];
            short8v blv = *(const short8v*)&Bl[bi];
            #pragma unroll
            for (int m = 0; m < 4; ++m) {
                acc[m][nf] = __builtin_amdgcn_mfma_f32_16x16x32_bf16(cah[m], bh,  acc[m][nf], 0, 0, 0);
                acc[m][nf] = __builtin_amdgcn_mfma_f32_16x16x32_bf16(cah[m], blv, acc[m][nf], 0, 0, 0);
                acc[m][nf] = __builtin_amdgcn_mfma_f32_16x16x32_bf16(cal[m], bh,  acc[m][nf], 0, 0, 0);
            }
        }
        #pragma unroll
        for (int m = 0; m < 4; ++m) { cah[m] = nah[m]; cal[m] = nal[m]; }
    }

    // epilogue: D row=(l>>4)*4+r -> co, col=l&15 -> sp (verified m89 layout)
    const int rr = (l >> 4) * 4, cc = l & 15;
    #pragma unroll
    for (int m = 0; m < 4; ++m) {
        const int cb = co_w + 16 * m + rr;
        #pragma unroll
        for (int nf = 0; nf < 7; ++nf) {
            const int p = p0 + nf * 16 + cc;
            #pragma unroll
            for (int r = 0; r < 4; ++r) {
                ushort hi, lo; split_bf(acc[m][nf][r], hi, lo);
                dh[(size_t)(cb + r) * SP + p] = hi;
                dl[(size_t)(cb + r) * SP + p] = lo;
            }
        }
    }
}

// ---------------------------------------------------------------------------
// gemm_a_mfma v4 (unchanged — direct stage, no cross-barrier prefetch)
// ---------------------------------------------------------------------------
__global__ __launch_bounds__(256, 2)
void gemm_a_mfma(const ushort* __restrict__ h1h, const ushort* __restrict__ h1l,
                 const ushort* __restrict__ hnh, const ushort* __restrict__ hnl,
                 float* __restrict__ attn)
{
    __shared__ __align__(16) ushort Ah[64][64];
    __shared__ __align__(16) ushort Al[64][64];
    __shared__ __align__(16) ushort Bh[64][64];
    __shared__ __align__(16) ushort Bl[64][64];
    const int tid = threadIdx.x;
    const int w = tid >> 6, l = tid & 63;
    const int wn = w >> 1, wm = w & 1;              // wave grid 2n x 2m
    const int img = blockIdx.x, tile = blockIdx.y;
    const int n0 = (tile & 3) * 64, m0 = (tile >> 2) * 64;

    const ushort* __restrict__ Ahg = h1h + ((size_t)img * COUT + n0) * SP;
    const ushort* __restrict__ Alg = h1l + ((size_t)img * COUT + n0) * SP;
    const ushort* __restrict__ Bhg = hnh + ((size_t)img * COUT + m0) * SP;
    const ushort* __restrict__ Blg = hnl + ((size_t)img * COUT + m0) * SP;

    f32x4 acc[2][2];
    #pragma unroll
    for (int i = 0; i < 2; ++i)
        #pragma unroll
        for (int j = 0; j < 2; ++j) acc[i][j] = (f32x4){0.f, 0.f, 0.f, 0.f};

    const int ap = tid >> 7, arow = (tid & 127) >> 1, ag0 = (tid & 1) * 4;
    const ushort* __restrict__ Asrc = ap ? Alg : Ahg;
    ushort (* __restrict__ Adst)[64] = ap ? Al : Ah;
    const ushort* __restrict__ Bsrc = ap ? Blg : Bhg;
    ushort (* __restrict__ Bdst)[64] = ap ? Bl : Bh;

    const ushort* aptr = Asrc + (size_t)arow * SP + ag0 * 8;
    const ushort* bptr = Bsrc + (size_t)arow * SP + ag0 * 8;

    for (int k0 = 0; k0 < SP; k0 += 64) {
        #pragma unroll
        for (int j = 0; j < 4; ++j) {
            uint4 va = ((const uint4*)(aptr + k0))[j];
            *(uint4*)&Adst[arow][SWZ(arow, ag0 + j)] = va;
            uint4 vb = ((const uint4*)(bptr + k0))[j];
            *(uint4*)&Bdst[arow][SWZ(arow, ag0 + j)] = vb;
        }
        __syncthreads();

        #pragma unroll
        for (int ks = 0; ks < 2; ++ks) {
            const int grp = ks * 4 + (l >> 4);
            short8v ahf[2], alf[2], bhf[2], blf[2];
            #pragma unroll
            for (int i = 0; i < 2; ++i) {
                const int ar_ = 32 * wn + 16 * i + (l & 15);
                ahf[i] = *(const short8v*)&Ah[ar_][SWZ(ar_, grp)];
                alf[i] = *(const short8v*)&Al[ar_][SWZ(ar_, grp)];
                const int br_ = 32 * wm + 16 * i + (l & 15);
                bhf[i] = *(const short8v*)&Bh[br_][SWZ(br_, grp)];
                blf[i] = *(const short8v*)&Bl[br_][SWZ(br_, grp)];
            }
            #pragma unroll
            for (int i = 0; i < 2; ++i)
                #pragma unroll
                for (int j = 0; j < 2; ++j) {
                    acc[i][j] = __builtin_amdgcn_mfma_f32_16x16x32_bf16(ahf[i], bhf[j], acc[i][j], 0, 0, 0);
                    acc[i][j] = __builtin_amdgcn_mfma_f32_16x16x32_bf16(ahf[i], blf[j], acc[i][j], 0, 0, 0);
                    acc[i][j] = __builtin_amdgcn_mfma_f32_16x16x32_bf16(alf[i], bhf[j], acc[i][j], 0, 0, 0);
                }
        }
        __syncthreads();
    }

    const int rr = (l >> 4) * 4, cc = l & 15;
    float* __restrict__ aimg = attn + (size_t)img * COUT * COUT;
    #pragma unroll
    for (int i = 0; i < 2; ++i) {
        const int nb = n0 + 32 * wn + 16 * i + rr;
        #pragma unroll
        for (int j = 0; j < 2; ++j) {
            const int m = m0 + 32 * wm + 16 * j + cc;
            #pragma unroll
            for (int r = 0; r < 4; ++r) {
                float v = acc[i][j][r];
                v = (v >= 0.f) ? v : NEG_SLOPE * v;
                aimg[(size_t)(nb + r) * COUT + m] = v;
            }
        }
    }
}

// ---------------------------------------------------------------------------
// softmax over axis n (dim=1) per (b,m) column, in place. (unchanged)
// ---------------------------------------------------------------------------
__global__ __launch_bounds__(64)
void softmax_k(float* __restrict__ attn)
{
    const int b = blockIdx.y;
    const int m = blockIdx.x * 64 + threadIdx.x;
    float* a = attn + (size_t)b * COUT * COUT;
    float mx = -1e30f;
    for (int n_ = 0; n_ < COUT; ++n_) mx = fmaxf(mx, a[n_ * COUT + m]);
    float s = 0.f;
    for (int n_ = 0; n_ < COUT; ++n_) s += expf(a[n_ * COUT + m] - mx);
    float inv = 1.f / s;
    for (int n_ = 0; n_ < COUT; ++n_)
        a[n_ * COUT + m] = expf(a[n_ * COUT + m] - mx) * inv;
}

// ---------------------------------------------------------------------------
// gemm_agg_mfma v2: out[n][f] = 0.1 * sum_m attn[n][m]*h1[m][f] + 0.9 * h1[n][f]
// SINGLE-PASS bf16: attn rows are convex combos (softmax) -> operand bf16
// rounding contributes |dout| <~ 5e-4 (vs threshold 0.102, current 0.0156).
// A = attn -> bf16 hi only; B = h1 hi plane only; 1 MFMA per (nf,mf) (was 3).
// LDS halved (34.5 KB) -> (256,4), 4 blocks/CU. Blend still exact hi+lo.
// ---------------------------------------------------------------------------
__global__ __launch_bounds__(256, 4)
void gemm_agg_mfma(const float* __restrict__ attn,
                   const ushort* __restrict__ h1h, const ushort* __restrict__ h1l,
                   float* __restrict__ out)
{
    __shared__ __align__(16) ushort Ah[128][72];
    __shared__ __align__(16) ushort Bh[112][72];
    const int tid = threadIdx.x, w = tid >> 6, l = tid & 63;
    const int f0 = blockIdx.x * 112;
    const int n0 = blockIdx.y * 128;
    const int img = blockIdx.z;

    const float*  __restrict__ A  = attn + (size_t)img * COUT * COUT;
    const ushort* __restrict__ Hh = h1h + (size_t)img * COUT * SP;
    const ushort* __restrict__ Hl = h1l + (size_t)img * COUT * SP;

    f32x4 acc[2][7];
    #pragma unroll
    for (int nf = 0; nf < 2; ++nf)
        #pragma unroll
        for (int mf = 0; mf < 7; ++mf) acc[nf][mf] = (f32x4){0.f, 0.f, 0.f, 0.f};

    const int ar = tid >> 1, ac = (tid & 1) * 32;    // A: 128 rows x 2 halves
    const int bm = (tid & 127) >> 1, bf = (tid & 1) * 56;  // B: threads < 128

    for (int k0 = 0; k0 < COUT; k0 += 64) {
        {   // A: attn[n0+ar][k0+ac..+31] f32 -> bf16 hi -> Ah (packed b32)
            const float* g = A + (size_t)(n0 + ar) * COUT + k0 + ac;
            uint* dh = (uint*)&Ah[ar][ac];
            #pragma unroll
            for (int q = 0; q < 8; ++q) {
                float4 v = *(const float4*)(g + 4 * q);
                dh[2 * q]     = (uint)bf_hi(v.x) | ((uint)bf_hi(v.y) << 16);
                dh[2 * q + 1] = (uint)bf_hi(v.z) | ((uint)bf_hi(v.w) << 16);
            }
        }
        if (tid < 128) {  // B: Hh[k0+bm][f0+bf..+55] -> transpose -> Bh[f][bm]
            const ushort* g = Hh + (size_t)(k0 + bm) * SP + f0 + bf;
            #pragma unroll
            for (int q = 0; q < 7; ++q) {
                uint4 v = *(const uint4*)(g + 8 * q);
                const ushort* vp = (const ushort*)&v;
                #pragma unroll
                for (int e = 0; e < 8; ++e)
                    Bh[bf + 8 * q + e][bm] = vp[e];
            }
        }
        __syncthreads();
        #pragma unroll
        for (int ks = 0; ks < 2; ++ks) {
            const int kb = ks * 32 + (l >> 4) * 8;
            short8v ah[2];
            #pragma unroll
            for (int nf = 0; nf < 2; ++nf) {
                const int row = 32 * w + 16 * nf + (l & 15);
                ah[nf] = *(const short8v*)&Ah[row][kb];
            }
            #pragma unroll
            for (int mf = 0; mf < 7; ++mf) {
                const int br = mf * 16 + (l & 15);
                short8v bh = *(const short8v*)&Bh[br][kb];
                #pragma unroll
                for (int nf = 0; nf < 2; ++nf)
                    acc[nf][mf] = __builtin_amdgcn_mfma_f32_16x16x32_bf16(ah[nf], bh, acc[nf][mf], 0, 0, 0);
            }
        }
        __syncthreads();
    }

    const int rr = (l >> 4) * 4, cc = l & 15;
    float* __restrict__ orow = out + (size_t)img * COUT * SP;
    #pragma unroll
    for (int nf = 0; nf < 2; ++nf) {
        const int nb = n0 + 32 * w + 16 * nf + rr;
        #pragma unroll
        for (int mf = 0; mf < 7; ++mf) {
            const int f = f0 + 16 * mf + cc;
            #pragma unroll
            for (int r = 0; r < 4; ++r) {
                const int n = nb + r;
                float h = bfr(Hh[(size_t)n * SP + f]) + bfr(Hl[(size_t)n * SP + f]);
                orow[(size_t)n * SP + f] = 0.1f * acc[nf][mf][r] + 0.9f * h;
            }
        }
    }
}

// ---------------------------------------------------------------------------
extern "C" void kernel_launch(void* const* d_in, const int* in_sizes, int n_in,
                              void* d_out, int out_size, void* d_ws, size_t ws_size,
                              hipStream_t stream)
{
    const float* x    = (const float*)d_in[0];
    const float* nn   = (const float*)d_in[1];
    const float* W    = (const float*)d_in[2];
    const float* bias = (const float*)d_in[3];
    float* out = (float*)d_out;

    // ws (111.2 MB): h1b_hi (51.4) | h1b_lo (51.4) | zone (8.39):
    //   conv phase: Wf hi/lo (1.2 MB); gemm phase: attn f32 (overlaps dead Wf).
    ushort* h1b_hi = (ushort*)d_ws;
    ushort* h1b_lo = h1b_hi + (size_t)NB * COUT * SP;
    char*   zone   = (char*)(h1b_lo + (size_t)NB * COUT * SP);
    ushort* Wf_hi  = (ushort*)zone;
    ushort* Wf_lo  = Wf_hi + 9 * 256 * 64;
    float*  attn   = (float*)zone;          // overwrites Wf after convs complete
    // d_out (102.8 MB): hnb_hi | hnb_lo until gemm_agg_mfma overwrites with out f32.
    ushort* hnb_hi = (ushort*)d_out;
    ushort* hnb_lo = hnb_hi + (size_t)NB * COUT * SP;

    pack_w    <<<576, 256, 0, stream>>>(W, Wf_hi, Wf_lo);
    conv_fused<<<dim3(28, 2 * NB), 256, 0, stream>>>(x, nn, Wf_hi, Wf_lo, bias,
                                                     h1b_hi, h1b_lo, hnb_hi, hnb_lo);
    gemm_a_mfma  <<<dim3(32, 16),    256, 0, stream>>>(h1b_hi, h1b_lo, hnb_hi, hnb_lo, attn);
    softmax_k    <<<dim3(4, NB),     64,  0, stream>>>(attn);
    gemm_agg_mfma<<<dim3(28, 2, NB), 256, 0, stream>>>(attn, h1b_hi, h1b_lo, out);
}

// Round 20
// 364.248 us; speedup vs baseline: 1.0216x; 1.0216x over previous
//
#include <hip/hip_runtime.h>
#include <hip/hip_bf16.h>
#include <cstddef>

#define SP 3136          // 56*56
#define CIN 64
#define COUT 256
#define NB 32
#define NEG_SLOPE 0.01f

typedef __attribute__((ext_vector_type(8))) short short8v;  // 8 bf16 (4 VGPRs)
typedef __attribute__((ext_vector_type(4))) float f32x4;    // MFMA accumulator

__device__ __forceinline__ float bfr(ushort h) {
    union { uint u; float f; } c; c.u = ((uint)h) << 16; return c.f;
}
__device__ __forceinline__ void split_bf(float v, ushort& hi, ushort& lo) {
    __hip_bfloat16 h = __float2bfloat16(v);
    float r = v - __bfloat162float(h);
    __hip_bfloat16 l2 = __float2bfloat16(r);
    hi = *(ushort*)&h; lo = *(ushort*)&l2;
}
__device__ __forceinline__ ushort bf_hi(float v) {
    __hip_bfloat16 h = __float2bfloat16(v);
    return *(ushort*)&h;
}

// XOR swizzle: logical 8-ushort group g of row -> physical ushort offset
#define SWZ(row, g) ((((g) ^ ((row) & 7))) * 8)

// direct global->LDS DMA, 16B per lane (dest = wave-uniform base + lane*16)
#define GLOAD_LDS(gp, lp) __builtin_amdgcn_global_load_lds(                    \
    (const __attribute__((address_space(1))) void*)(gp),                       \
    (__attribute__((address_space(3))) void*)(lp), 16, 0, 0)

// ---------------------------------------------------------------------------
// pack_w: W[co][ci][ky][kx] f32 -> fragment-contiguous planes (unchanged)
// ---------------------------------------------------------------------------
__global__ __launch_bounds__(256)
void pack_w(const float* __restrict__ W, ushort* __restrict__ wh, ushort* __restrict__ wl)
{
    const int id = blockIdx.x * 256 + threadIdx.x;   // 147456 = 9*256*64
    const int ci = id & 63, co = (id >> 6) & 255, tap = id >> 14;
    float v = W[(size_t)(co * 64 + ci) * 9 + tap];
    ushort hi, lo; split_bf(v, hi, lo);
    const int ks = ci >> 5, cig = (ci >> 3) & 3, ce = ci & 7;
    const size_t o = (((size_t)(tap * 2 + ks) * 4 + cig) * 256 + co) * 8 + ce;
    wh[o] = hi; wl[o] = lo;
}

// ---------------------------------------------------------------------------
// conv_fused v4 (unchanged — pipelined A-gather, ~154 µs, MfmaUtil 52%)
// ---------------------------------------------------------------------------
__global__ __launch_bounds__(256, 2)
void conv_fused(const float* __restrict__ xsrc, const float* __restrict__ nsrc,
                const ushort* __restrict__ Wf_hi, const ushort* __restrict__ Wf_lo,
                const float* __restrict__ bias,
                ushort* __restrict__ h1h, ushort* __restrict__ h1l,
                ushort* __restrict__ hnh, ushort* __restrict__ hnl)
{
    __shared__ __align__(16) ushort Bh[4 * 58 * 64]; // 29 KB
    __shared__ __align__(16) ushort Bl[4 * 58 * 64]; // 29 KB
    const int tid = threadIdx.x;
    const int w = tid >> 6, l = tid & 63;
    const int rp  = blockIdx.x;                      // 0..27
    const int img = blockIdx.y;                      // 0..63
    const int imgb = img & (NB - 1);
    const int y0 = rp * 2, p0 = rp * 112;
    const int co_w = w * 64;                         // wave's co base (4x64=256)

    const float* __restrict__ src = (img < NB ? xsrc : nsrc) + (size_t)imgb * CIN * SP;
    ushort* __restrict__ dh = (img < NB ? h1h : hnh) + (size_t)imgb * COUT * SP;
    ushort* __restrict__ dl = (img < NB ? h1l : hnl) + (size_t)imgb * COUT * SP;

    int sy[4];
    #pragma unroll
    for (int j = 0; j < 4; ++j) sy[j] = (y0 + 55 + j) % 56;   // padded row y0+j

    // ---- stage B once: raw f32 -> split bf16 -> LDS [j][x][ci] swizzled ----
    {
        const int ci = tid >> 2, seg = tid & 3;      // 64 ci x 4 col-segments(14)
        #pragma unroll
        for (int j = 0; j < 4; ++j) {
            const float* r = src + (size_t)ci * SP + sy[j] * 56 + seg * 14;
            #pragma unroll
            for (int c = 0; c < 14; ++c) {
                float v = r[c];
                ushort hi, lo; split_bf(v, hi, lo);
                const int x = seg * 14 + c + 1;      // padded col = orig col + 1
                const int idx = ((j * 58 + x) << 6) + (((ci >> 3) ^ (x & 7)) << 3) + (ci & 7);
                Bh[idx] = hi; Bl[idx] = lo;
            }
        }
        // wrap columns: x=0 <- orig col 55, x=57 <- orig col 0 (512 slots, 2/thr)
        #pragma unroll
        for (int s = 0; s < 2; ++s) {
            const int slot = tid * 2 + s;
            const int j2 = slot >> 7, ci2 = (slot >> 1) & 63, side = slot & 1;
            const float* r2 = src + (size_t)ci2 * SP + sy[j2] * 56;
            const float v = side ? r2[0] : r2[55];
            const int x = side ? 57 : 0;
            ushort hi, lo; split_bf(v, hi, lo);
            const int idx = ((j2 * 58 + x) << 6) + (((ci2 >> 3) ^ (x & 7)) << 3) + (ci2 & 7);
            Bh[idx] = hi; Bl[idx] = lo;
        }
    }
    __syncthreads();                                 // the ONLY barrier

    f32x4 acc[4][7];
    {
        const int rr = (l >> 4) * 4;
        #pragma unroll
        for (int m = 0; m < 4; ++m) {
            const int cb = co_w + 16 * m + rr;
            f32x4 bv = { bias[cb], bias[cb + 1], bias[cb + 2], bias[cb + 3] };
            #pragma unroll
            for (int nf = 0; nf < 7; ++nf) acc[m][nf] = bv;
        }
    }

    // per-nf spatial decomposition (lane-dependent, tap-invariant)
    int b58[7], bx[7];
    #pragma unroll
    for (int nf = 0; nf < 7; ++nf) {
        const int sp = nf * 16 + (l & 15);           // 0..111
        const int ry = (sp >= 56) ? 1 : 0;
        const int xx = sp - ry * 56;
        b58[nf] = ry * 58 + xx;
        bx[nf]  = xx;
    }

    // A-fragment base offsets (iter stride = 4*256*8 = 8192 ushorts)
    size_t aoff[4];
    #pragma unroll
    for (int m = 0; m < 4; ++m)
        aoff[m] = ((size_t)(l >> 4) * 256 + co_w + 16 * m + (l & 15)) * 8;

    short8v cah[4], cal[4];                          // current A fragments
    #pragma unroll
    for (int m = 0; m < 4; ++m) {
        cah[m] = *(const short8v*)(Wf_hi + aoff[m]);
        cal[m] = *(const short8v*)(Wf_lo + aoff[m]);
    }

    for (int it = 0; it < 18; ++it) {                // it = tap*2 + ks
        const int tap = it >> 1, ks = it & 1;
        const int dy = tap / 3, dx = tap - dy * 3;
        const int toff = dy * 58 + dx;
        const int grp = ks * 4 + (l >> 4);

        short8v nah[4], nal[4];                      // prefetch next iter's A
        {
            const size_t po = (size_t)(it < 17 ? it + 1 : it) * 8192;
            #pragma unroll
            for (int m = 0; m < 4; ++m) {
                nah[m] = *(const short8v*)(Wf_hi + aoff[m] + po);
                nal[m] = *(const short8v*)(Wf_lo + aoff[m] + po);
            }
        }

        #pragma unroll
        for (int nf = 0; nf < 7; ++nf) {
            const int x  = bx[nf] + dx;
            const int bi = ((b58[nf] + toff) << 6) + ((grp ^ (x & 7)) << 3);
            short8v bh  = *(const short8v*)&Bh[bi];
            short8v blv = *(const short8v*)&Bl[bi];
            #pragma unroll
            for (int m = 0; m < 4; ++m) {
                acc[m][nf] = __builtin_amdgcn_mfma_f32_16x16x32_bf16(cah[m], bh,  acc[m][nf], 0, 0, 0);
                acc[m][nf] = __builtin_amdgcn_mfma_f32_16x16x32_bf16(cah[m], blv, acc[m][nf], 0, 0, 0);
                acc[m][nf] = __builtin_amdgcn_mfma_f32_16x16x32_bf16(cal[m], bh,  acc[m][nf], 0, 0, 0);
            }
        }
        #pragma unroll
        for (int m = 0; m < 4; ++m) { cah[m] = nah[m]; cal[m] = nal[m]; }
    }

    // epilogue: D row=(l>>4)*4+r -> co, col=l&15 -> sp (verified m89 layout)
    const int rr = (l >> 4) * 4, cc = l & 15;
    #pragma unroll
    for (int m = 0; m < 4; ++m) {
        const int cb = co_w + 16 * m + rr;
        #pragma unroll
        for (int nf = 0; nf < 7; ++nf) {
            const int p = p0 + nf * 16 + cc;
            #pragma unroll
            for (int r = 0; r < 4; ++r) {
                ushort hi, lo; split_bf(acc[m][nf][r], hi, lo);
                dh[(size_t)(cb + r) * SP + p] = hi;
                dl[(size_t)(cb + r) * SP + p] = lo;
            }
        }
    }
}

// ---------------------------------------------------------------------------
// gemm_a_mfma v5: staging via global_load_lds DMA (no VGPR round-trip).
// Wave w stages matrix w (Ah/Al/Bh/Bl, 64 rows x 64 ushorts linear LDS);
// lane l: row = 8*seg + (l>>3), phys grp = l&7, global src group = (l&7)^(l>>3)
// (same XOR involution on source and read — data identical to v4).
// Compute identical to v4. 256 thr = 4 waves (2n x 2m), tile 64n x 64m.
// ---------------------------------------------------------------------------
__global__ __launch_bounds__(256, 2)
void gemm_a_mfma(const ushort* __restrict__ h1h, const ushort* __restrict__ h1l,
                 const ushort* __restrict__ hnh, const ushort* __restrict__ hnl,
                 float* __restrict__ attn)
{
    __shared__ __align__(16) ushort Ah[64][64];
    __shared__ __align__(16) ushort Al[64][64];
    __shared__ __align__(16) ushort Bh[64][64];
    __shared__ __align__(16) ushort Bl[64][64];
    const int tid = threadIdx.x;
    const int w = tid >> 6, l = tid & 63;
    const int wn = w >> 1, wm = w & 1;              // wave grid 2n x 2m
    const int img = blockIdx.x, tile = blockIdx.y;
    const int n0 = (tile & 3) * 64, m0 = (tile >> 2) * 64;

    const ushort* __restrict__ msrc0 = h1h + ((size_t)img * COUT + n0) * SP;
    const ushort* __restrict__ msrc1 = h1l + ((size_t)img * COUT + n0) * SP;
    const ushort* __restrict__ msrc2 = hnh + ((size_t)img * COUT + m0) * SP;
    const ushort* __restrict__ msrc3 = hnl + ((size_t)img * COUT + m0) * SP;

    f32x4 acc[2][2];
    #pragma unroll
    for (int i = 0; i < 2; ++i)
        #pragma unroll
        for (int j = 0; j < 2; ++j) acc[i][j] = (f32x4){0.f, 0.f, 0.f, 0.f};

    // DMA staging setup: wave w owns matrix w; 8 segments of 8 rows each.
    const int lr = l >> 3, gp = l & 7;               // lane row-in-seg, phys grp
    const int glog = gp ^ lr;                        // swizzled source group
    const ushort* wsrc = (w == 0) ? msrc0 : (w == 1) ? msrc1 : (w == 2) ? msrc2 : msrc3;
    ushort* wlds = (w == 0) ? &Ah[0][0] : (w == 1) ? &Al[0][0] : (w == 2) ? &Bh[0][0] : &Bl[0][0];

    const ushort* gptr[8];
    ushort* lptr[8];
    #pragma unroll
    for (int t = 0; t < 8; ++t) {
        gptr[t] = wsrc + (size_t)(t * 8 + lr) * SP + glog * 8;
        lptr[t] = wlds + t * 8 * 64;                 // wave-uniform base
    }

    for (int k0 = 0; k0 < SP; k0 += 64) {
        #pragma unroll
        for (int t = 0; t < 8; ++t)
            GLOAD_LDS(gptr[t] + k0, lptr[t]);
        __syncthreads();                             // drains vmcnt before barrier

        #pragma unroll
        for (int ks = 0; ks < 2; ++ks) {
            const int grp = ks * 4 + (l >> 4);
            short8v ahf[2], alf[2], bhf[2], blf[2];
            #pragma unroll
            for (int i = 0; i < 2; ++i) {
                const int ar_ = 32 * wn + 16 * i + (l & 15);
                ahf[i] = *(const short8v*)&Ah[ar_][SWZ(ar_, grp)];
                alf[i] = *(const short8v*)&Al[ar_][SWZ(ar_, grp)];
                const int br_ = 32 * wm + 16 * i + (l & 15);
                bhf[i] = *(const short8v*)&Bh[br_][SWZ(br_, grp)];
                blf[i] = *(const short8v*)&Bl[br_][SWZ(br_, grp)];
            }
            #pragma unroll
            for (int i = 0; i < 2; ++i)
                #pragma unroll
                for (int j = 0; j < 2; ++j) {
                    acc[i][j] = __builtin_amdgcn_mfma_f32_16x16x32_bf16(ahf[i], bhf[j], acc[i][j], 0, 0, 0);
                    acc[i][j] = __builtin_amdgcn_mfma_f32_16x16x32_bf16(ahf[i], blf[j], acc[i][j], 0, 0, 0);
                    acc[i][j] = __builtin_amdgcn_mfma_f32_16x16x32_bf16(alf[i], bhf[j], acc[i][j], 0, 0, 0);
                }
        }
        __syncthreads();
    }

    const int rr = (l >> 4) * 4, cc = l & 15;
    float* __restrict__ aimg = attn + (size_t)img * COUT * COUT;
    #pragma unroll
    for (int i = 0; i < 2; ++i) {
        const int nb = n0 + 32 * wn + 16 * i + rr;
        #pragma unroll
        for (int j = 0; j < 2; ++j) {
            const int m = m0 + 32 * wm + 16 * j + cc;
            #pragma unroll
            for (int r = 0; r < 4; ++r) {
                float v = acc[i][j][r];
                v = (v >= 0.f) ? v : NEG_SLOPE * v;
                aimg[(size_t)(nb + r) * COUT + m] = v;
            }
        }
    }
}

// ---------------------------------------------------------------------------
// softmax over axis n (dim=1) per (b,m) column, in place. (unchanged)
// ---------------------------------------------------------------------------
__global__ __launch_bounds__(64)
void softmax_k(float* __restrict__ attn)
{
    const int b = blockIdx.y;
    const int m = blockIdx.x * 64 + threadIdx.x;
    float* a = attn + (size_t)b * COUT * COUT;
    float mx = -1e30f;
    for (int n_ = 0; n_ < COUT; ++n_) mx = fmaxf(mx, a[n_ * COUT + m]);
    float s = 0.f;
    for (int n_ = 0; n_ < COUT; ++n_) s += expf(a[n_ * COUT + m] - mx);
    float inv = 1.f / s;
    for (int n_ = 0; n_ < COUT; ++n_)
        a[n_ * COUT + m] = expf(a[n_ * COUT + m] - mx) * inv;
}

// ---------------------------------------------------------------------------
// gemm_agg_mfma v3: single-pass bf16 (r19, numerically verified) + B-transpose
// staging distributed over ALL 256 threads (was 128; 28 scalar writes/thread
// via 7 x uint2 reads). A staging and compute unchanged.
// ---------------------------------------------------------------------------
__global__ __launch_bounds__(256, 4)
void gemm_agg_mfma(const float* __restrict__ attn,
                   const ushort* __restrict__ h1h, const ushort* __restrict__ h1l,
                   float* __restrict__ out)
{
    __shared__ __align__(16) ushort Ah[128][72];
    __shared__ __align__(16) ushort Bh[112][72];
    const int tid = threadIdx.x, w = tid >> 6, l = tid & 63;
    const int f0 = blockIdx.x * 112;
    const int n0 = blockIdx.y * 128;
    const int img = blockIdx.z;

    const float*  __restrict__ A  = attn + (size_t)img * COUT * COUT;
    const ushort* __restrict__ Hh = h1h + (size_t)img * COUT * SP;
    const ushort* __restrict__ Hl = h1l + (size_t)img * COUT * SP;

    f32x4 acc[2][7];
    #pragma unroll
    for (int nf = 0; nf < 2; ++nf)
        #pragma unroll
        for (int mf = 0; mf < 7; ++mf) acc[nf][mf] = (f32x4){0.f, 0.f, 0.f, 0.f};

    const int ar = tid >> 1, ac = (tid & 1) * 32;    // A: 128 rows x 2 halves
    const int bm = tid >> 2, bq = tid & 3, bfo = bq * 28;  // B: 64 rows x 4 quarters

    for (int k0 = 0; k0 < COUT; k0 += 64) {
        {   // A: attn[n0+ar][k0+ac..+31] f32 -> bf16 hi -> Ah (packed b32)
            const float* g = A + (size_t)(n0 + ar) * COUT + k0 + ac;
            uint* dh = (uint*)&Ah[ar][ac];
            #pragma unroll
            for (int q = 0; q < 8; ++q) {
                float4 v = *(const float4*)(g + 4 * q);
                dh[2 * q]     = (uint)bf_hi(v.x) | ((uint)bf_hi(v.y) << 16);
                dh[2 * q + 1] = (uint)bf_hi(v.z) | ((uint)bf_hi(v.w) << 16);
            }
        }
        {   // B: Hh[k0+bm][f0+bfo..+27] -> transpose -> Bh[f][bm] (all 256 thr)
            const ushort* g = Hh + (size_t)(k0 + bm) * SP + f0 + bfo;
            #pragma unroll
            for (int e = 0; e < 7; ++e) {
                uint2 v = *(const uint2*)(g + 4 * e);
                const ushort* vp = (const ushort*)&v;
                #pragma unroll
                for (int j = 0; j < 4; ++j)
                    Bh[bfo + 4 * e + j][bm] = vp[j];
            }
        }
        __syncthreads();
        #pragma unroll
        for (int ks = 0; ks < 2; ++ks) {
            const int kb = ks * 32 + (l >> 4) * 8;
            short8v ah[2];
            #pragma unroll
            for (int nf = 0; nf < 2; ++nf) {
                const int row = 32 * w + 16 * nf + (l & 15);
                ah[nf] = *(const short8v*)&Ah[row][kb];
            }
            #pragma unroll
            for (int mf = 0; mf < 7; ++mf) {
                const int br = mf * 16 + (l & 15);
                short8v bh = *(const short8v*)&Bh[br][kb];
                #pragma unroll
                for (int nf = 0; nf < 2; ++nf)
                    acc[nf][mf] = __builtin_amdgcn_mfma_f32_16x16x32_bf16(ah[nf], bh, acc[nf][mf], 0, 0, 0);
            }
        }
        __syncthreads();
    }

    const int rr = (l >> 4) * 4, cc = l & 15;
    float* __restrict__ orow = out + (size_t)img * COUT * SP;
    #pragma unroll
    for (int nf = 0; nf < 2; ++nf) {
        const int nb = n0 + 32 * w + 16 * nf + rr;
        #pragma unroll
        for (int mf = 0; mf < 7; ++mf) {
            const int f = f0 + 16 * mf + cc;
            #pragma unroll
            for (int r = 0; r < 4; ++r) {
                const int n = nb + r;
                float h = bfr(Hh[(size_t)n * SP + f]) + bfr(Hl[(size_t)n * SP + f]);
                orow[(size_t)n * SP + f] = 0.1f * acc[nf][mf][r] + 0.9f * h;
            }
        }
    }
}

// ---------------------------------------------------------------------------
extern "C" void kernel_launch(void* const* d_in, const int* in_sizes, int n_in,
                              void* d_out, int out_size, void* d_ws, size_t ws_size,
                              hipStream_t stream)
{
    const float* x    = (const float*)d_in[0];
    const float* nn   = (const float*)d_in[1];
    const float* W    = (const float*)d_in[2];
    const float* bias = (const float*)d_in[3];
    float* out = (float*)d_out;

    // ws (111.2 MB): h1b_hi (51.4) | h1b_lo (51.4) | zone (8.39):
    //   conv phase: Wf hi/lo (1.2 MB); gemm phase: attn f32 (overlaps dead Wf).
    ushort* h1b_hi = (ushort*)d_ws;
    ushort* h1b_lo = h1b_hi + (size_t)NB * COUT * SP;
    char*   zone   = (char*)(h1b_lo + (size_t)NB * COUT * SP);
    ushort* Wf_hi  = (ushort*)zone;
    ushort* Wf_lo  = Wf_hi + 9 * 256 * 64;
    float*  attn   = (float*)zone;          // overwrites Wf after convs complete
    // d_out (102.8 MB): hnb_hi | hnb_lo until gemm_agg_mfma overwrites with out f32.
    ushort* hnb_hi = (ushort*)d_out;
    ushort* hnb_lo = hnb_hi + (size_t)NB * COUT * SP;

    pack_w    <<<576, 256, 0, stream>>>(W, Wf_hi, Wf_lo);
    conv_fused<<<dim3(28, 2 * NB), 256, 0, stream>>>(x, nn, Wf_hi, Wf_lo, bias,
                                                     h1b_hi, h1b_lo, hnb_hi, hnb_lo);
    gemm_a_mfma  <<<dim3(32, 16),    256, 0, stream>>>(h1b_hi, h1b_lo, hnb_hi, hnb_lo, attn);
    softmax_k    <<<dim3(4, NB),     64,  0, stream>>>(attn);
    gemm_agg_mfma<<<dim3(28, 2, NB), 256, 0, stream>>>(attn, h1b_hi, h1b_lo, out);
}

// Round 21
// 336.582 us; speedup vs baseline: 1.1056x; 1.0822x over previous
//
#include <hip/hip_runtime.h>
#include <hip/hip_bf16.h>
#include <cstddef>

#define SP 3136          // 56*56
#define CIN 64
#define COUT 256
#define NB 32
#define NEG_SLOPE 0.01f

typedef __attribute__((ext_vector_type(8))) short short8v;  // 8 bf16 (4 VGPRs)
typedef __attribute__((ext_vector_type(4))) float f32x4;    // MFMA accumulator

__device__ __forceinline__ float bfr(ushort h) {
    union { uint u; float f; } c; c.u = ((uint)h) << 16; return c.f;
}
__device__ __forceinline__ void split_bf(float v, ushort& hi, ushort& lo) {
    __hip_bfloat16 h = __float2bfloat16(v);
    float r = v - __bfloat162float(h);
    __hip_bfloat16 l2 = __float2bfloat16(r);
    hi = *(ushort*)&h; lo = *(ushort*)&l2;
}
__device__ __forceinline__ ushort bf_hi(float v) {
    __hip_bfloat16 h = __float2bfloat16(v);
    return *(ushort*)&h;
}

// XOR swizzle: logical 8-ushort group g of row -> physical ushort offset
#define SWZ(row, g) ((((g) ^ ((row) & 7))) * 8)

// direct global->LDS DMA, 16B per lane (dest = wave-uniform base + lane*16)
#define GLOAD_LDS(gp, lp) __builtin_amdgcn_global_load_lds(                    \
    (const __attribute__((address_space(1))) void*)(gp),                       \
    (__attribute__((address_space(3))) void*)(lp), 16, 0, 0)

// ---------------------------------------------------------------------------
// pack_w: W[co][ci][ky][kx] f32 -> fragment-contiguous planes (unchanged)
// ---------------------------------------------------------------------------
__global__ __launch_bounds__(256)
void pack_w(const float* __restrict__ W, ushort* __restrict__ wh, ushort* __restrict__ wl)
{
    const int id = blockIdx.x * 256 + threadIdx.x;   // 147456 = 9*256*64
    const int ci = id & 63, co = (id >> 6) & 255, tap = id >> 14;
    float v = W[(size_t)(co * 64 + ci) * 9 + tap];
    ushort hi, lo; split_bf(v, hi, lo);
    const int ks = ci >> 5, cig = (ci >> 3) & 3, ce = ci & 7;
    const size_t o = (((size_t)(tap * 2 + ks) * 4 + cig) * 256 + co) * 8 + ce;
    wh[o] = hi; wl[o] = lo;
}

// ---------------------------------------------------------------------------
// conv_fused v5: 3x3 circular conv, bf16 MFMA, barrier-free tap loop.
// r20 change: 2-pass bf16 (drop W_lo·B_hi — weight-rounding term).
// Error budget: dh1 ~ 0.002 abs -> blend +0.0018, logit d~0.14 -> agg +<0.014;
// total ~0.05 vs threshold 0.102. W_lo never loaded -> A-gather halves.
// ---------------------------------------------------------------------------
__global__ __launch_bounds__(256, 2)
void conv_fused(const float* __restrict__ xsrc, const float* __restrict__ nsrc,
                const ushort* __restrict__ Wf_hi, const ushort* __restrict__ Wf_lo,
                const float* __restrict__ bias,
                ushort* __restrict__ h1h, ushort* __restrict__ h1l,
                ushort* __restrict__ hnh, ushort* __restrict__ hnl)
{
    __shared__ __align__(16) ushort Bh[4 * 58 * 64]; // 29 KB
    __shared__ __align__(16) ushort Bl[4 * 58 * 64]; // 29 KB
    const int tid = threadIdx.x;
    const int w = tid >> 6, l = tid & 63;
    const int rp  = blockIdx.x;                      // 0..27
    const int img = blockIdx.y;                      // 0..63
    const int imgb = img & (NB - 1);
    const int y0 = rp * 2, p0 = rp * 112;
    const int co_w = w * 64;                         // wave's co base (4x64=256)

    const float* __restrict__ src = (img < NB ? xsrc : nsrc) + (size_t)imgb * CIN * SP;
    ushort* __restrict__ dh = (img < NB ? h1h : hnh) + (size_t)imgb * COUT * SP;
    ushort* __restrict__ dl = (img < NB ? h1l : hnl) + (size_t)imgb * COUT * SP;

    int sy[4];
    #pragma unroll
    for (int j = 0; j < 4; ++j) sy[j] = (y0 + 55 + j) % 56;   // padded row y0+j

    // ---- stage B once: raw f32 -> split bf16 -> LDS [j][x][ci] swizzled ----
    {
        const int ci = tid >> 2, seg = tid & 3;      // 64 ci x 4 col-segments(14)
        #pragma unroll
        for (int j = 0; j < 4; ++j) {
            const float* r = src + (size_t)ci * SP + sy[j] * 56 + seg * 14;
            #pragma unroll
            for (int c = 0; c < 14; ++c) {
                float v = r[c];
                ushort hi, lo; split_bf(v, hi, lo);
                const int x = seg * 14 + c + 1;      // padded col = orig col + 1
                const int idx = ((j * 58 + x) << 6) + (((ci >> 3) ^ (x & 7)) << 3) + (ci & 7);
                Bh[idx] = hi; Bl[idx] = lo;
            }
        }
        // wrap columns: x=0 <- orig col 55, x=57 <- orig col 0 (512 slots, 2/thr)
        #pragma unroll
        for (int s = 0; s < 2; ++s) {
            const int slot = tid * 2 + s;
            const int j2 = slot >> 7, ci2 = (slot >> 1) & 63, side = slot & 1;
            const float* r2 = src + (size_t)ci2 * SP + sy[j2] * 56;
            const float v = side ? r2[0] : r2[55];
            const int x = side ? 57 : 0;
            ushort hi, lo; split_bf(v, hi, lo);
            const int idx = ((j2 * 58 + x) << 6) + (((ci2 >> 3) ^ (x & 7)) << 3) + (ci2 & 7);
            Bh[idx] = hi; Bl[idx] = lo;
        }
    }
    __syncthreads();                                 // the ONLY barrier

    f32x4 acc[4][7];
    {
        const int rr = (l >> 4) * 4;
        #pragma unroll
        for (int m = 0; m < 4; ++m) {
            const int cb = co_w + 16 * m + rr;
            f32x4 bv = { bias[cb], bias[cb + 1], bias[cb + 2], bias[cb + 3] };
            #pragma unroll
            for (int nf = 0; nf < 7; ++nf) acc[m][nf] = bv;
        }
    }

    // per-nf spatial decomposition (lane-dependent, tap-invariant)
    int b58[7], bx[7];
    #pragma unroll
    for (int nf = 0; nf < 7; ++nf) {
        const int sp = nf * 16 + (l & 15);           // 0..111
        const int ry = (sp >= 56) ? 1 : 0;
        const int xx = sp - ry * 56;
        b58[nf] = ry * 58 + xx;
        bx[nf]  = xx;
    }

    // A-fragment base offsets (iter stride = 4*256*8 = 8192 ushorts)
    size_t aoff[4];
    #pragma unroll
    for (int m = 0; m < 4; ++m)
        aoff[m] = ((size_t)(l >> 4) * 256 + co_w + 16 * m + (l & 15)) * 8;

    short8v cah[4];                                  // current A fragments (hi only)
    #pragma unroll
    for (int m = 0; m < 4; ++m)
        cah[m] = *(const short8v*)(Wf_hi + aoff[m]);

    for (int it = 0; it < 18; ++it) {                // it = tap*2 + ks
        const int tap = it >> 1, ks = it & 1;
        const int dy = tap / 3, dx = tap - dy * 3;
        const int toff = dy * 58 + dx;
        const int grp = ks * 4 + (l >> 4);

        short8v nah[4];                              // prefetch next iter's A
        {
            const size_t po = (size_t)(it < 17 ? it + 1 : it) * 8192;
            #pragma unroll
            for (int m = 0; m < 4; ++m)
                nah[m] = *(const short8v*)(Wf_hi + aoff[m] + po);
        }

        #pragma unroll
        for (int nf = 0; nf < 7; ++nf) {
            const int x  = bx[nf] + dx;
            const int bi = ((b58[nf] + toff) << 6) + ((grp ^ (x & 7)) << 3);
            short8v bh  = *(const short8v*)&Bh[bi];
            short8v blv = *(const short8v*)&Bl[bi];
            #pragma unroll
            for (int m = 0; m < 4; ++m) {
                acc[m][nf] = __builtin_amdgcn_mfma_f32_16x16x32_bf16(cah[m], bh,  acc[m][nf], 0, 0, 0);
                acc[m][nf] = __builtin_amdgcn_mfma_f32_16x16x32_bf16(cah[m], blv, acc[m][nf], 0, 0, 0);
            }
        }
        #pragma unroll
        for (int m = 0; m < 4; ++m) cah[m] = nah[m];
    }

    // epilogue: D row=(l>>4)*4+r -> co, col=l&15 -> sp (verified m89 layout)
    const int rr = (l >> 4) * 4, cc = l & 15;
    #pragma unroll
    for (int m = 0; m < 4; ++m) {
        const int cb = co_w + 16 * m + rr;
        #pragma unroll
        for (int nf = 0; nf < 7; ++nf) {
            const int p = p0 + nf * 16 + cc;
            #pragma unroll
            for (int r = 0; r < 4; ++r) {
                ushort hi, lo; split_bf(acc[m][nf][r], hi, lo);
                dh[(size_t)(cb + r) * SP + p] = hi;
                dl[(size_t)(cb + r) * SP + p] = lo;
            }
        }
    }
}

// ---------------------------------------------------------------------------
// gemm_a_mfma v5 (unchanged from round 20 — global_load_lds DMA staging)
// ---------------------------------------------------------------------------
__global__ __launch_bounds__(256, 2)
void gemm_a_mfma(const ushort* __restrict__ h1h, const ushort* __restrict__ h1l,
                 const ushort* __restrict__ hnh, const ushort* __restrict__ hnl,
                 float* __restrict__ attn)
{
    __shared__ __align__(16) ushort Ah[64][64];
    __shared__ __align__(16) ushort Al[64][64];
    __shared__ __align__(16) ushort Bh[64][64];
    __shared__ __align__(16) ushort Bl[64][64];
    const int tid = threadIdx.x;
    const int w = tid >> 6, l = tid & 63;
    const int wn = w >> 1, wm = w & 1;              // wave grid 2n x 2m
    const int img = blockIdx.x, tile = blockIdx.y;
    const int n0 = (tile & 3) * 64, m0 = (tile >> 2) * 64;

    const ushort* __restrict__ msrc0 = h1h + ((size_t)img * COUT + n0) * SP;
    const ushort* __restrict__ msrc1 = h1l + ((size_t)img * COUT + n0) * SP;
    const ushort* __restrict__ msrc2 = hnh + ((size_t)img * COUT + m0) * SP;
    const ushort* __restrict__ msrc3 = hnl + ((size_t)img * COUT + m0) * SP;

    f32x4 acc[2][2];
    #pragma unroll
    for (int i = 0; i < 2; ++i)
        #pragma unroll
        for (int j = 0; j < 2; ++j) acc[i][j] = (f32x4){0.f, 0.f, 0.f, 0.f};

    // DMA staging setup: wave w owns matrix w; 8 segments of 8 rows each.
    const int lr = l >> 3, gp = l & 7;               // lane row-in-seg, phys grp
    const int glog = gp ^ lr;                        // swizzled source group
    const ushort* wsrc = (w == 0) ? msrc0 : (w == 1) ? msrc1 : (w == 2) ? msrc2 : msrc3;
    ushort* wlds = (w == 0) ? &Ah[0][0] : (w == 1) ? &Al[0][0] : (w == 2) ? &Bh[0][0] : &Bl[0][0];

    const ushort* gptr[8];
    ushort* lptr[8];
    #pragma unroll
    for (int t = 0; t < 8; ++t) {
        gptr[t] = wsrc + (size_t)(t * 8 + lr) * SP + glog * 8;
        lptr[t] = wlds + t * 8 * 64;                 // wave-uniform base
    }

    for (int k0 = 0; k0 < SP; k0 += 64) {
        #pragma unroll
        for (int t = 0; t < 8; ++t)
            GLOAD_LDS(gptr[t] + k0, lptr[t]);
        __syncthreads();                             // drains vmcnt before barrier

        #pragma unroll
        for (int ks = 0; ks < 2; ++ks) {
            const int grp = ks * 4 + (l >> 4);
            short8v ahf[2], alf[2], bhf[2], blf[2];
            #pragma unroll
            for (int i = 0; i < 2; ++i) {
                const int ar_ = 32 * wn + 16 * i + (l & 15);
                ahf[i] = *(const short8v*)&Ah[ar_][SWZ(ar_, grp)];
                alf[i] = *(const short8v*)&Al[ar_][SWZ(ar_, grp)];
                const int br_ = 32 * wm + 16 * i + (l & 15);
                bhf[i] = *(const short8v*)&Bh[br_][SWZ(br_, grp)];
                blf[i] = *(const short8v*)&Bl[br_][SWZ(br_, grp)];
            }
            #pragma unroll
            for (int i = 0; i < 2; ++i)
                #pragma unroll
                for (int j = 0; j < 2; ++j) {
                    acc[i][j] = __builtin_amdgcn_mfma_f32_16x16x32_bf16(ahf[i], bhf[j], acc[i][j], 0, 0, 0);
                    acc[i][j] = __builtin_amdgcn_mfma_f32_16x16x32_bf16(ahf[i], blf[j], acc[i][j], 0, 0, 0);
                    acc[i][j] = __builtin_amdgcn_mfma_f32_16x16x32_bf16(alf[i], bhf[j], acc[i][j], 0, 0, 0);
                }
        }
        __syncthreads();
    }

    const int rr = (l >> 4) * 4, cc = l & 15;
    float* __restrict__ aimg = attn + (size_t)img * COUT * COUT;
    #pragma unroll
    for (int i = 0; i < 2; ++i) {
        const int nb = n0 + 32 * wn + 16 * i + rr;
        #pragma unroll
        for (int j = 0; j < 2; ++j) {
            const int m = m0 + 32 * wm + 16 * j + cc;
            #pragma unroll
            for (int r = 0; r < 4; ++r) {
                float v = acc[i][j][r];
                v = (v >= 0.f) ? v : NEG_SLOPE * v;
                aimg[(size_t)(nb + r) * COUT + m] = v;
            }
        }
    }
}

// ---------------------------------------------------------------------------
// softmax over axis n (dim=1) per (b,m) column, in place. (unchanged)
// ---------------------------------------------------------------------------
__global__ __launch_bounds__(64)
void softmax_k(float* __restrict__ attn)
{
    const int b = blockIdx.y;
    const int m = blockIdx.x * 64 + threadIdx.x;
    float* a = attn + (size_t)b * COUT * COUT;
    float mx = -1e30f;
    for (int n_ = 0; n_ < COUT; ++n_) mx = fmaxf(mx, a[n_ * COUT + m]);
    float s = 0.f;
    for (int n_ = 0; n_ < COUT; ++n_) s += expf(a[n_ * COUT + m] - mx);
    float inv = 1.f / s;
    for (int n_ = 0; n_ < COUT; ++n_)
        a[n_ * COUT + m] = expf(a[n_ * COUT + m] - mx) * inv;
}

// ---------------------------------------------------------------------------
// gemm_agg_mfma v3 (unchanged from round 20 — single-pass bf16, distributed
// B-transpose staging)
// ---------------------------------------------------------------------------
__global__ __launch_bounds__(256, 4)
void gemm_agg_mfma(const float* __restrict__ attn,
                   const ushort* __restrict__ h1h, const ushort* __restrict__ h1l,
                   float* __restrict__ out)
{
    __shared__ __align__(16) ushort Ah[128][72];
    __shared__ __align__(16) ushort Bh[112][72];
    const int tid = threadIdx.x, w = tid >> 6, l = tid & 63;
    const int f0 = blockIdx.x * 112;
    const int n0 = blockIdx.y * 128;
    const int img = blockIdx.z;

    const float*  __restrict__ A  = attn + (size_t)img * COUT * COUT;
    const ushort* __restrict__ Hh = h1h + (size_t)img * COUT * SP;
    const ushort* __restrict__ Hl = h1l + (size_t)img * COUT * SP;

    f32x4 acc[2][7];
    #pragma unroll
    for (int nf = 0; nf < 2; ++nf)
        #pragma unroll
        for (int mf = 0; mf < 7; ++mf) acc[nf][mf] = (f32x4){0.f, 0.f, 0.f, 0.f};

    const int ar = tid >> 1, ac = (tid & 1) * 32;    // A: 128 rows x 2 halves
    const int bm = tid >> 2, bq = tid & 3, bfo = bq * 28;  // B: 64 rows x 4 quarters

    for (int k0 = 0; k0 < COUT; k0 += 64) {
        {   // A: attn[n0+ar][k0+ac..+31] f32 -> bf16 hi -> Ah (packed b32)
            const float* g = A + (size_t)(n0 + ar) * COUT + k0 + ac;
            uint* dh = (uint*)&Ah[ar][ac];
            #pragma unroll
            for (int q = 0; q < 8; ++q) {
                float4 v = *(const float4*)(g + 4 * q);
                dh[2 * q]     = (uint)bf_hi(v.x) | ((uint)bf_hi(v.y) << 16);
                dh[2 * q + 1] = (uint)bf_hi(v.z) | ((uint)bf_hi(v.w) << 16);
            }
        }
        {   // B: Hh[k0+bm][f0+bfo..+27] -> transpose -> Bh[f][bm] (all 256 thr)
            const ushort* g = Hh + (size_t)(k0 + bm) * SP + f0 + bfo;
            #pragma unroll
            for (int e = 0; e < 7; ++e) {
                uint2 v = *(const uint2*)(g + 4 * e);
                const ushort* vp = (const ushort*)&v;
                #pragma unroll
                for (int j = 0; j < 4; ++j)
                    Bh[bfo + 4 * e + j][bm] = vp[j];
            }
        }
        __syncthreads();
        #pragma unroll
        for (int ks = 0; ks < 2; ++ks) {
            const int kb = ks * 32 + (l >> 4) * 8;
            short8v ah[2];
            #pragma unroll
            for (int nf = 0; nf < 2; ++nf) {
                const int row = 32 * w + 16 * nf + (l & 15);
                ah[nf] = *(const short8v*)&Ah[row][kb];
            }
            #pragma unroll
            for (int mf = 0; mf < 7; ++mf) {
                const int br = mf * 16 + (l & 15);
                short8v bh = *(const short8v*)&Bh[br][kb];
                #pragma unroll
                for (int nf = 0; nf < 2; ++nf)
                    acc[nf][mf] = __builtin_amdgcn_mfma_f32_16x16x32_bf16(ah[nf], bh, acc[nf][mf], 0, 0, 0);
            }
        }
        __syncthreads();
    }

    const int rr = (l >> 4) * 4, cc = l & 15;
    float* __restrict__ orow = out + (size_t)img * COUT * SP;
    #pragma unroll
    for (int nf = 0; nf < 2; ++nf) {
        const int nb = n0 + 32 * w + 16 * nf + rr;
        #pragma unroll
        for (int mf = 0; mf < 7; ++mf) {
            const int f = f0 + 16 * mf + cc;
            #pragma unroll
            for (int r = 0; r < 4; ++r) {
                const int n = nb + r;
                float h = bfr(Hh[(size_t)n * SP + f]) + bfr(Hl[(size_t)n * SP + f]);
                orow[(size_t)n * SP + f] = 0.1f * acc[nf][mf][r] + 0.9f * h;
            }
        }
    }
}

// ---------------------------------------------------------------------------
extern "C" void kernel_launch(void* const* d_in, const int* in_sizes, int n_in,
                              void* d_out, int out_size, void* d_ws, size_t ws_size,
                              hipStream_t stream)
{
    const float* x    = (const float*)d_in[0];
    const float* nn   = (const float*)d_in[1];
    const float* W    = (const float*)d_in[2];
    const float* bias = (const float*)d_in[3];
    float* out = (float*)d_out;

    // ws (111.2 MB): h1b_hi (51.4) | h1b_lo (51.4) | zone (8.39):
    //   conv phase: Wf hi/lo (1.2 MB); gemm phase: attn f32 (overlaps dead Wf).
    ushort* h1b_hi = (ushort*)d_ws;
    ushort* h1b_lo = h1b_hi + (size_t)NB * COUT * SP;
    char*   zone   = (char*)(h1b_lo + (size_t)NB * COUT * SP);
    ushort* Wf_hi  = (ushort*)zone;
    ushort* Wf_lo  = Wf_hi + 9 * 256 * 64;
    float*  attn   = (float*)zone;          // overwrites Wf after convs complete
    // d_out (102.8 MB): hnb_hi | hnb_lo until gemm_agg_mfma overwrites with out f32.
    ushort* hnb_hi = (ushort*)d_out;
    ushort* hnb_lo = hnb_hi + (size_t)NB * COUT * SP;

    pack_w    <<<576, 256, 0, stream>>>(W, Wf_hi, Wf_lo);
    conv_fused<<<dim3(28, 2 * NB), 256, 0, stream>>>(x, nn, Wf_hi, Wf_lo, bias,
                                                     h1b_hi, h1b_lo, hnb_hi, hnb_lo);
    gemm_a_mfma  <<<dim3(32, 16),    256, 0, stream>>>(h1b_hi, h1b_lo, hnb_hi, hnb_lo, attn);
    softmax_k    <<<dim3(4, NB),     64,  0, stream>>>(attn);
    gemm_agg_mfma<<<dim3(28, 2, NB), 256, 0, stream>>>(attn, h1b_hi, h1b_lo, out);
}

// Round 22
// 316.294 us; speedup vs baseline: 1.1765x; 1.0641x over previous
//
#include <hip/hip_runtime.h>
#include <hip/hip_bf16.h>
#include <cstddef>

#define SP 3136          // 56*56
#define CIN 64
#define COUT 256
#define NB 32
#define NEG_SLOPE 0.01f

typedef __attribute__((ext_vector_type(8))) short short8v;  // 8 bf16 (4 VGPRs)
typedef __attribute__((ext_vector_type(4))) float f32x4;    // MFMA accumulator

__device__ __forceinline__ float bfr(ushort h) {
    union { uint u; float f; } c; c.u = ((uint)h) << 16; return c.f;
}
__device__ __forceinline__ void split_bf(float v, ushort& hi, ushort& lo) {
    __hip_bfloat16 h = __float2bfloat16(v);
    float r = v - __bfloat162float(h);
    __hip_bfloat16 l2 = __float2bfloat16(r);
    hi = *(ushort*)&h; lo = *(ushort*)&l2;
}
__device__ __forceinline__ ushort bf_hi(float v) {
    __hip_bfloat16 h = __float2bfloat16(v);
    return *(ushort*)&h;
}

// XOR swizzle: logical 8-ushort group g of row -> physical ushort offset
#define SWZ(row, g) ((((g) ^ ((row) & 7))) * 8)

// direct global->LDS DMA, 16B per lane (dest = wave-uniform base + lane*16)
#define GLOAD_LDS(gp, lp) __builtin_amdgcn_global_load_lds(                    \
    (const __attribute__((address_space(1))) void*)(gp),                       \
    (__attribute__((address_space(3))) void*)(lp), 16, 0, 0)

// ---------------------------------------------------------------------------
// pack_w: W[co][ci][ky][kx] f32 -> fragment-contiguous planes (unchanged)
// ---------------------------------------------------------------------------
__global__ __launch_bounds__(256)
void pack_w(const float* __restrict__ W, ushort* __restrict__ wh, ushort* __restrict__ wl)
{
    const int id = blockIdx.x * 256 + threadIdx.x;   // 147456 = 9*256*64
    const int ci = id & 63, co = (id >> 6) & 255, tap = id >> 14;
    float v = W[(size_t)(co * 64 + ci) * 9 + tap];
    ushort hi, lo; split_bf(v, hi, lo);
    const int ks = ci >> 5, cig = (ci >> 3) & 3, ce = ci & 7;
    const size_t o = (((size_t)(tap * 2 + ks) * 4 + cig) * 256 + co) * 8 + ce;
    wh[o] = hi; wl[o] = lo;
}

// ---------------------------------------------------------------------------
// conv_fused v6: 2-pass bf16 MFMA conv (r21) + r22 change: the n-branch
// (img >= NB) skips lo-plane stores — hn_lo is consumed by nothing after
// gemm_a moves to 2-pass. Write traffic 201 -> 151 MB.
// ---------------------------------------------------------------------------
__global__ __launch_bounds__(256, 2)
void conv_fused(const float* __restrict__ xsrc, const float* __restrict__ nsrc,
                const ushort* __restrict__ Wf_hi, const ushort* __restrict__ Wf_lo,
                const float* __restrict__ bias,
                ushort* __restrict__ h1h, ushort* __restrict__ h1l,
                ushort* __restrict__ hnh)
{
    __shared__ __align__(16) ushort Bh[4 * 58 * 64]; // 29 KB
    __shared__ __align__(16) ushort Bl[4 * 58 * 64]; // 29 KB
    const int tid = threadIdx.x;
    const int w = tid >> 6, l = tid & 63;
    const int rp  = blockIdx.x;                      // 0..27
    const int img = blockIdx.y;                      // 0..63
    const int imgb = img & (NB - 1);
    const int y0 = rp * 2, p0 = rp * 112;
    const int co_w = w * 64;                         // wave's co base (4x64=256)
    const bool isX = (img < NB);

    const float* __restrict__ src = (isX ? xsrc : nsrc) + (size_t)imgb * CIN * SP;
    ushort* __restrict__ dh = (isX ? h1h : hnh) + (size_t)imgb * COUT * SP;
    ushort* __restrict__ dl = h1l + (size_t)imgb * COUT * SP;   // used only if isX

    int sy[4];
    #pragma unroll
    for (int j = 0; j < 4; ++j) sy[j] = (y0 + 55 + j) % 56;   // padded row y0+j

    // ---- stage B once: raw f32 -> split bf16 -> LDS [j][x][ci] swizzled ----
    {
        const int ci = tid >> 2, seg = tid & 3;      // 64 ci x 4 col-segments(14)
        #pragma unroll
        for (int j = 0; j < 4; ++j) {
            const float* r = src + (size_t)ci * SP + sy[j] * 56 + seg * 14;
            #pragma unroll
            for (int c = 0; c < 14; ++c) {
                float v = r[c];
                ushort hi, lo; split_bf(v, hi, lo);
                const int x = seg * 14 + c + 1;      // padded col = orig col + 1
                const int idx = ((j * 58 + x) << 6) + (((ci >> 3) ^ (x & 7)) << 3) + (ci & 7);
                Bh[idx] = hi; Bl[idx] = lo;
            }
        }
        // wrap columns: x=0 <- orig col 55, x=57 <- orig col 0 (512 slots, 2/thr)
        #pragma unroll
        for (int s = 0; s < 2; ++s) {
            const int slot = tid * 2 + s;
            const int j2 = slot >> 7, ci2 = (slot >> 1) & 63, side = slot & 1;
            const float* r2 = src + (size_t)ci2 * SP + sy[j2] * 56;
            const float v = side ? r2[0] : r2[55];
            const int x = side ? 57 : 0;
            ushort hi, lo; split_bf(v, hi, lo);
            const int idx = ((j2 * 58 + x) << 6) + (((ci2 >> 3) ^ (x & 7)) << 3) + (ci2 & 7);
            Bh[idx] = hi; Bl[idx] = lo;
        }
    }
    __syncthreads();                                 // the ONLY barrier

    f32x4 acc[4][7];
    {
        const int rr = (l >> 4) * 4;
        #pragma unroll
        for (int m = 0; m < 4; ++m) {
            const int cb = co_w + 16 * m + rr;
            f32x4 bv = { bias[cb], bias[cb + 1], bias[cb + 2], bias[cb + 3] };
            #pragma unroll
            for (int nf = 0; nf < 7; ++nf) acc[m][nf] = bv;
        }
    }

    // per-nf spatial decomposition (lane-dependent, tap-invariant)
    int b58[7], bx[7];
    #pragma unroll
    for (int nf = 0; nf < 7; ++nf) {
        const int sp = nf * 16 + (l & 15);           // 0..111
        const int ry = (sp >= 56) ? 1 : 0;
        const int xx = sp - ry * 56;
        b58[nf] = ry * 58 + xx;
        bx[nf]  = xx;
    }

    // A-fragment base offsets (iter stride = 4*256*8 = 8192 ushorts)
    size_t aoff[4];
    #pragma unroll
    for (int m = 0; m < 4; ++m)
        aoff[m] = ((size_t)(l >> 4) * 256 + co_w + 16 * m + (l & 15)) * 8;

    short8v cah[4];                                  // current A fragments (hi only)
    #pragma unroll
    for (int m = 0; m < 4; ++m)
        cah[m] = *(const short8v*)(Wf_hi + aoff[m]);

    for (int it = 0; it < 18; ++it) {                // it = tap*2 + ks
        const int tap = it >> 1, ks = it & 1;
        const int dy = tap / 3, dx = tap - dy * 3;
        const int toff = dy * 58 + dx;
        const int grp = ks * 4 + (l >> 4);

        short8v nah[4];                              // prefetch next iter's A
        {
            const size_t po = (size_t)(it < 17 ? it + 1 : it) * 8192;
            #pragma unroll
            for (int m = 0; m < 4; ++m)
                nah[m] = *(const short8v*)(Wf_hi + aoff[m] + po);
        }

        #pragma unroll
        for (int nf = 0; nf < 7; ++nf) {
            const int x  = bx[nf] + dx;
            const int bi = ((b58[nf] + toff) << 6) + ((grp ^ (x & 7)) << 3);
            short8v bh  = *(const short8v*)&Bh[bi];
            short8v blv = *(const short8v*)&Bl[bi];
            #pragma unroll
            for (int m = 0; m < 4; ++m) {
                acc[m][nf] = __builtin_amdgcn_mfma_f32_16x16x32_bf16(cah[m], bh,  acc[m][nf], 0, 0, 0);
                acc[m][nf] = __builtin_amdgcn_mfma_f32_16x16x32_bf16(cah[m], blv, acc[m][nf], 0, 0, 0);
            }
        }
        #pragma unroll
        for (int m = 0; m < 4; ++m) cah[m] = nah[m];
    }

    // epilogue: D row=(l>>4)*4+r -> co, col=l&15 -> sp (verified m89 layout)
    const int rr = (l >> 4) * 4, cc = l & 15;
    #pragma unroll
    for (int m = 0; m < 4; ++m) {
        const int cb = co_w + 16 * m + rr;
        #pragma unroll
        for (int nf = 0; nf < 7; ++nf) {
            const int p = p0 + nf * 16 + cc;
            #pragma unroll
            for (int r = 0; r < 4; ++r) {
                ushort hi, lo; split_bf(acc[m][nf][r], hi, lo);
                dh[(size_t)(cb + r) * SP + p] = hi;
                if (isX) dl[(size_t)(cb + r) * SP + p] = lo;   // block-uniform branch
            }
        }
    }
}

// ---------------------------------------------------------------------------
// gemm_a_mfma v6: 2-pass (H_hi·N_hi + H_lo·N_hi); hn_lo never read.
// LDS 24 KB (Ah/Al/Bh). Staging: 24 one-KB segment-units over 4 waves
// (6 GLOAD_LDS per wave). Compute per (i,j): 2 MFMA (was 3).
// ---------------------------------------------------------------------------
__global__ __launch_bounds__(256, 2)
void gemm_a_mfma(const ushort* __restrict__ h1h, const ushort* __restrict__ h1l,
                 const ushort* __restrict__ hnh,
                 float* __restrict__ attn)
{
    __shared__ __align__(16) ushort Ah[64][64];
    __shared__ __align__(16) ushort Al[64][64];
    __shared__ __align__(16) ushort Bh[64][64];
    const int tid = threadIdx.x;
    const int w = tid >> 6, l = tid & 63;
    const int wn = w >> 1, wm = w & 1;              // wave grid 2n x 2m
    const int img = blockIdx.x, tile = blockIdx.y;
    const int n0 = (tile & 3) * 64, m0 = (tile >> 2) * 64;

    const ushort* __restrict__ mat0 = h1h + ((size_t)img * COUT + n0) * SP;
    const ushort* __restrict__ mat1 = h1l + ((size_t)img * COUT + n0) * SP;
    const ushort* __restrict__ mat2 = hnh + ((size_t)img * COUT + m0) * SP;

    f32x4 acc[2][2];
    #pragma unroll
    for (int i = 0; i < 2; ++i)
        #pragma unroll
        for (int j = 0; j < 2; ++j) acc[i][j] = (f32x4){0.f, 0.f, 0.f, 0.f};

    // staging: 24 units (mat u>>3, seg u&7); wave w -> units 6w..6w+5.
    const int lr = l >> 3, gp = l & 7;               // lane row-in-seg, phys grp
    const int glog = gp ^ lr;                        // swizzled source group
    const ushort* gptr[6];
    ushort* lptr[6];
    #pragma unroll
    for (int t = 0; t < 6; ++t) {
        const int u = 6 * w + t, mat = u >> 3, seg = u & 7;
        const ushort* ms = (mat == 0) ? mat0 : (mat == 1) ? mat1 : mat2;
        ushort* lb = (mat == 0) ? &Ah[0][0] : (mat == 1) ? &Al[0][0] : &Bh[0][0];
        gptr[t] = ms + (size_t)(seg * 8 + lr) * SP + glog * 8;
        lptr[t] = lb + seg * 8 * 64;                 // wave-uniform base
    }

    for (int k0 = 0; k0 < SP; k0 += 64) {
        #pragma unroll
        for (int t = 0; t < 6; ++t)
            GLOAD_LDS(gptr[t] + k0, lptr[t]);
        __syncthreads();                             // drains vmcnt before barrier

        #pragma unroll
        for (int ks = 0; ks < 2; ++ks) {
            const int grp = ks * 4 + (l >> 4);
            short8v ahf[2], alf[2], bhf[2];
            #pragma unroll
            for (int i = 0; i < 2; ++i) {
                const int ar_ = 32 * wn + 16 * i + (l & 15);
                ahf[i] = *(const short8v*)&Ah[ar_][SWZ(ar_, grp)];
                alf[i] = *(const short8v*)&Al[ar_][SWZ(ar_, grp)];
                const int br_ = 32 * wm + 16 * i + (l & 15);
                bhf[i] = *(const short8v*)&Bh[br_][SWZ(br_, grp)];
            }
            #pragma unroll
            for (int i = 0; i < 2; ++i)
                #pragma unroll
                for (int j = 0; j < 2; ++j) {
                    acc[i][j] = __builtin_amdgcn_mfma_f32_16x16x32_bf16(ahf[i], bhf[j], acc[i][j], 0, 0, 0);
                    acc[i][j] = __builtin_amdgcn_mfma_f32_16x16x32_bf16(alf[i], bhf[j], acc[i][j], 0, 0, 0);
                }
        }
        __syncthreads();
    }

    const int rr = (l >> 4) * 4, cc = l & 15;
    float* __restrict__ aimg = attn + (size_t)img * COUT * COUT;
    #pragma unroll
    for (int i = 0; i < 2; ++i) {
        const int nb = n0 + 32 * wn + 16 * i + rr;
        #pragma unroll
        for (int j = 0; j < 2; ++j) {
            const int m = m0 + 32 * wm + 16 * j + cc;
            #pragma unroll
            for (int r = 0; r < 4; ++r) {
                float v = acc[i][j][r];
                v = (v >= 0.f) ? v : NEG_SLOPE * v;
                aimg[(size_t)(nb + r) * COUT + m] = v;
            }
        }
    }
}

// ---------------------------------------------------------------------------
// softmax over axis n (dim=1) per (b,m) column, in place. (unchanged)
// ---------------------------------------------------------------------------
__global__ __launch_bounds__(64)
void softmax_k(float* __restrict__ attn)
{
    const int b = blockIdx.y;
    const int m = blockIdx.x * 64 + threadIdx.x;
    float* a = attn + (size_t)b * COUT * COUT;
    float mx = -1e30f;
    for (int n_ = 0; n_ < COUT; ++n_) mx = fmaxf(mx, a[n_ * COUT + m]);
    float s = 0.f;
    for (int n_ = 0; n_ < COUT; ++n_) s += expf(a[n_ * COUT + m] - mx);
    float inv = 1.f / s;
    for (int n_ = 0; n_ < COUT; ++n_)
        a[n_ * COUT + m] = expf(a[n_ * COUT + m] - mx) * inv;
}

// ---------------------------------------------------------------------------
// gemm_agg_mfma v3 (unchanged — single-pass bf16, distributed B staging)
// ---------------------------------------------------------------------------
__global__ __launch_bounds__(256, 4)
void gemm_agg_mfma(const float* __restrict__ attn,
                   const ushort* __restrict__ h1h, const ushort* __restrict__ h1l,
                   float* __restrict__ out)
{
    __shared__ __align__(16) ushort Ah[128][72];
    __shared__ __align__(16) ushort Bh[112][72];
    const int tid = threadIdx.x, w = tid >> 6, l = tid & 63;
    const int f0 = blockIdx.x * 112;
    const int n0 = blockIdx.y * 128;
    const int img = blockIdx.z;

    const float*  __restrict__ A  = attn + (size_t)img * COUT * COUT;
    const ushort* __restrict__ Hh = h1h + (size_t)img * COUT * SP;
    const ushort* __restrict__ Hl = h1l + (size_t)img * COUT * SP;

    f32x4 acc[2][7];
    #pragma unroll
    for (int nf = 0; nf < 2; ++nf)
        #pragma unroll
        for (int mf = 0; mf < 7; ++mf) acc[nf][mf] = (f32x4){0.f, 0.f, 0.f, 0.f};

    const int ar = tid >> 1, ac = (tid & 1) * 32;    // A: 128 rows x 2 halves
    const int bm = tid >> 2, bq = tid & 3, bfo = bq * 28;  // B: 64 rows x 4 quarters

    for (int k0 = 0; k0 < COUT; k0 += 64) {
        {   // A: attn[n0+ar][k0+ac..+31] f32 -> bf16 hi -> Ah (packed b32)
            const float* g = A + (size_t)(n0 + ar) * COUT + k0 + ac;
            uint* dh = (uint*)&Ah[ar][ac];
            #pragma unroll
            for (int q = 0; q < 8; ++q) {
                float4 v = *(const float4*)(g + 4 * q);
                dh[2 * q]     = (uint)bf_hi(v.x) | ((uint)bf_hi(v.y) << 16);
                dh[2 * q + 1] = (uint)bf_hi(v.z) | ((uint)bf_hi(v.w) << 16);
            }
        }
        {   // B: Hh[k0+bm][f0+bfo..+27] -> transpose -> Bh[f][bm] (all 256 thr)
            const ushort* g = Hh + (size_t)(k0 + bm) * SP + f0 + bfo;
            #pragma unroll
            for (int e = 0; e < 7; ++e) {
                uint2 v = *(const uint2*)(g + 4 * e);
                const ushort* vp = (const ushort*)&v;
                #pragma unroll
                for (int j = 0; j < 4; ++j)
                    Bh[bfo + 4 * e + j][bm] = vp[j];
            }
        }
        __syncthreads();
        #pragma unroll
        for (int ks = 0; ks < 2; ++ks) {
            const int kb = ks * 32 + (l >> 4) * 8;
            short8v ah[2];
            #pragma unroll
            for (int nf = 0; nf < 2; ++nf) {
                const int row = 32 * w + 16 * nf + (l & 15);
                ah[nf] = *(const short8v*)&Ah[row][kb];
            }
            #pragma unroll
            for (int mf = 0; mf < 7; ++mf) {
                const int br = mf * 16 + (l & 15);
                short8v bh = *(const short8v*)&Bh[br][kb];
                #pragma unroll
                for (int nf = 0; nf < 2; ++nf)
                    acc[nf][mf] = __builtin_amdgcn_mfma_f32_16x16x32_bf16(ah[nf], bh, acc[nf][mf], 0, 0, 0);
            }
        }
        __syncthreads();
    }

    const int rr = (l >> 4) * 4, cc = l & 15;
    float* __restrict__ orow = out + (size_t)img * COUT * SP;
    #pragma unroll
    for (int nf = 0; nf < 2; ++nf) {
        const int nb = n0 + 32 * w + 16 * nf + rr;
        #pragma unroll
        for (int mf = 0; mf < 7; ++mf) {
            const int f = f0 + 16 * mf + cc;
            #pragma unroll
            for (int r = 0; r < 4; ++r) {
                const int n = nb + r;
                float h = bfr(Hh[(size_t)n * SP + f]) + bfr(Hl[(size_t)n * SP + f]);
                orow[(size_t)n * SP + f] = 0.1f * acc[nf][mf][r] + 0.9f * h;
            }
        }
    }
}

// ---------------------------------------------------------------------------
extern "C" void kernel_launch(void* const* d_in, const int* in_sizes, int n_in,
                              void* d_out, int out_size, void* d_ws, size_t ws_size,
                              hipStream_t stream)
{
    const float* x    = (const float*)d_in[0];
    const float* nn   = (const float*)d_in[1];
    const float* W    = (const float*)d_in[2];
    const float* bias = (const float*)d_in[3];
    float* out = (float*)d_out;

    // ws (111.2 MB): h1b_hi (51.4) | h1b_lo (51.4) | zone (8.39):
    //   conv phase: Wf hi/lo (1.2 MB); gemm phase: attn f32 (overlaps dead Wf).
    ushort* h1b_hi = (ushort*)d_ws;
    ushort* h1b_lo = h1b_hi + (size_t)NB * COUT * SP;
    char*   zone   = (char*)(h1b_lo + (size_t)NB * COUT * SP);
    ushort* Wf_hi  = (ushort*)zone;
    ushort* Wf_lo  = Wf_hi + 9 * 256 * 64;
    float*  attn   = (float*)zone;          // overwrites Wf after convs complete
    // d_out (102.8 MB): hnb_hi (51.4) until gemm_agg_mfma overwrites with out f32.
    ushort* hnb_hi = (ushort*)d_out;

    pack_w    <<<576, 256, 0, stream>>>(W, Wf_hi, Wf_lo);
    conv_fused<<<dim3(28, 2 * NB), 256, 0, stream>>>(x, nn, Wf_hi, Wf_lo, bias,
                                                     h1b_hi, h1b_lo, hnb_hi);
    gemm_a_mfma  <<<dim3(32, 16),    256, 0, stream>>>(h1b_hi, h1b_lo, hnb_hi, attn);
    softmax_k    <<<dim3(4, NB),     64,  0, stream>>>(attn);
    gemm_agg_mfma<<<dim3(28, 2, NB), 256, 0, stream>>>(attn, h1b_hi, h1b_lo, out);
}

// Round 23
// 283.671 us; speedup vs baseline: 1.3118x; 1.1150x over previous
//
#include <hip/hip_runtime.h>
#include <hip/hip_bf16.h>
#include <cstddef>

#define SP 3136          // 56*56
#define CIN 64
#define COUT 256
#define NB 32
#define NEG_SLOPE 0.01f

typedef __attribute__((ext_vector_type(8))) short short8v;  // 8 bf16 (4 VGPRs)
typedef __attribute__((ext_vector_type(4))) float f32x4;    // MFMA accumulator

__device__ __forceinline__ float bfr(ushort h) {
    union { uint u; float f; } c; c.u = ((uint)h) << 16; return c.f;
}
__device__ __forceinline__ void split_bf(float v, ushort& hi, ushort& lo) {
    __hip_bfloat16 h = __float2bfloat16(v);
    float r = v - __bfloat162float(h);
    __hip_bfloat16 l2 = __float2bfloat16(r);
    hi = *(ushort*)&h; lo = *(ushort*)&l2;
}
__device__ __forceinline__ ushort bf_hi(float v) {
    __hip_bfloat16 h = __float2bfloat16(v);
    return *(ushort*)&h;
}

// XOR swizzle: logical 8-ushort group g of row -> physical ushort offset
#define SWZ(row, g) ((((g) ^ ((row) & 7))) * 8)

// direct global->LDS DMA, 16B per lane (dest = wave-uniform base + lane*16)
#define GLOAD_LDS(gp, lp) __builtin_amdgcn_global_load_lds(                    \
    (const __attribute__((address_space(1))) void*)(gp),                       \
    (__attribute__((address_space(3))) void*)(lp), 16, 0, 0)

// ---------------------------------------------------------------------------
// pack_w: W[co][ci][ky][kx] f32 -> fragment-contiguous hi plane (lo dead since
// conv v5; only wh is consumed)
// ---------------------------------------------------------------------------
__global__ __launch_bounds__(256)
void pack_w(const float* __restrict__ W, ushort* __restrict__ wh)
{
    const int id = blockIdx.x * 256 + threadIdx.x;   // 147456 = 9*256*64
    const int ci = id & 63, co = (id >> 6) & 255, tap = id >> 14;
    float v = W[(size_t)(co * 64 + ci) * 9 + tap];
    const int ks = ci >> 5, cig = (ci >> 3) & 3, ce = ci & 7;
    const size_t o = (((size_t)(tap * 2 + ks) * 4 + cig) * 256 + co) * 8 + ce;
    wh[o] = bf_hi(v);
}

// ---------------------------------------------------------------------------
// conv_fused v7: 2-pass bf16 MFMA conv; r23 change: NO lo-plane output at all
// (h1_lo dead after gemm_a 1-pass + bf16 blend). Epilogue = bf_hi only.
// WRITE 153 -> 102 MB.
// ---------------------------------------------------------------------------
__global__ __launch_bounds__(256, 2)
void conv_fused(const float* __restrict__ xsrc, const float* __restrict__ nsrc,
                const ushort* __restrict__ Wf_hi,
                const float* __restrict__ bias,
                ushort* __restrict__ h1h, ushort* __restrict__ hnh)
{
    __shared__ __align__(16) ushort Bh[4 * 58 * 64]; // 29 KB
    __shared__ __align__(16) ushort Bl[4 * 58 * 64]; // 29 KB
    const int tid = threadIdx.x;
    const int w = tid >> 6, l = tid & 63;
    const int rp  = blockIdx.x;                      // 0..27
    const int img = blockIdx.y;                      // 0..63
    const int imgb = img & (NB - 1);
    const int y0 = rp * 2, p0 = rp * 112;
    const int co_w = w * 64;                         // wave's co base (4x64=256)
    const bool isX = (img < NB);

    const float* __restrict__ src = (isX ? xsrc : nsrc) + (size_t)imgb * CIN * SP;
    ushort* __restrict__ dh = (isX ? h1h : hnh) + (size_t)imgb * COUT * SP;

    int sy[4];
    #pragma unroll
    for (int j = 0; j < 4; ++j) sy[j] = (y0 + 55 + j) % 56;   // padded row y0+j

    // ---- stage B once: raw f32 -> split bf16 -> LDS [j][x][ci] swizzled ----
    {
        const int ci = tid >> 2, seg = tid & 3;      // 64 ci x 4 col-segments(14)
        #pragma unroll
        for (int j = 0; j < 4; ++j) {
            const float* r = src + (size_t)ci * SP + sy[j] * 56 + seg * 14;
            #pragma unroll
            for (int c = 0; c < 14; ++c) {
                float v = r[c];
                ushort hi, lo; split_bf(v, hi, lo);
                const int x = seg * 14 + c + 1;      // padded col = orig col + 1
                const int idx = ((j * 58 + x) << 6) + (((ci >> 3) ^ (x & 7)) << 3) + (ci & 7);
                Bh[idx] = hi; Bl[idx] = lo;
            }
        }
        // wrap columns: x=0 <- orig col 55, x=57 <- orig col 0 (512 slots, 2/thr)
        #pragma unroll
        for (int s = 0; s < 2; ++s) {
            const int slot = tid * 2 + s;
            const int j2 = slot >> 7, ci2 = (slot >> 1) & 63, side = slot & 1;
            const float* r2 = src + (size_t)ci2 * SP + sy[j2] * 56;
            const float v = side ? r2[0] : r2[55];
            const int x = side ? 57 : 0;
            ushort hi, lo; split_bf(v, hi, lo);
            const int idx = ((j2 * 58 + x) << 6) + (((ci2 >> 3) ^ (x & 7)) << 3) + (ci2 & 7);
            Bh[idx] = hi; Bl[idx] = lo;
        }
    }
    __syncthreads();                                 // the ONLY barrier

    f32x4 acc[4][7];
    {
        const int rr = (l >> 4) * 4;
        #pragma unroll
        for (int m = 0; m < 4; ++m) {
            const int cb = co_w + 16 * m + rr;
            f32x4 bv = { bias[cb], bias[cb + 1], bias[cb + 2], bias[cb + 3] };
            #pragma unroll
            for (int nf = 0; nf < 7; ++nf) acc[m][nf] = bv;
        }
    }

    // per-nf spatial decomposition (lane-dependent, tap-invariant)
    int b58[7], bx[7];
    #pragma unroll
    for (int nf = 0; nf < 7; ++nf) {
        const int sp = nf * 16 + (l & 15);           // 0..111
        const int ry = (sp >= 56) ? 1 : 0;
        const int xx = sp - ry * 56;
        b58[nf] = ry * 58 + xx;
        bx[nf]  = xx;
    }

    // A-fragment base offsets (iter stride = 4*256*8 = 8192 ushorts)
    size_t aoff[4];
    #pragma unroll
    for (int m = 0; m < 4; ++m)
        aoff[m] = ((size_t)(l >> 4) * 256 + co_w + 16 * m + (l & 15)) * 8;

    short8v cah[4];                                  // current A fragments (hi only)
    #pragma unroll
    for (int m = 0; m < 4; ++m)
        cah[m] = *(const short8v*)(Wf_hi + aoff[m]);

    for (int it = 0; it < 18; ++it) {                // it = tap*2 + ks
        const int tap = it >> 1, ks = it & 1;
        const int dy = tap / 3, dx = tap - dy * 3;
        const int toff = dy * 58 + dx;
        const int grp = ks * 4 + (l >> 4);

        short8v nah[4];                              // prefetch next iter's A
        {
            const size_t po = (size_t)(it < 17 ? it + 1 : it) * 8192;
            #pragma unroll
            for (int m = 0; m < 4; ++m)
                nah[m] = *(const short8v*)(Wf_hi + aoff[m] + po);
        }

        #pragma unroll
        for (int nf = 0; nf < 7; ++nf) {
            const int x  = bx[nf] + dx;
            const int bi = ((b58[nf] + toff) << 6) + ((grp ^ (x & 7)) << 3);
            short8v bh  = *(const short8v*)&Bh[bi];
            short8v blv = *(const short8v*)&Bl[bi];
            #pragma unroll
            for (int m = 0; m < 4; ++m) {
                acc[m][nf] = __builtin_amdgcn_mfma_f32_16x16x32_bf16(cah[m], bh,  acc[m][nf], 0, 0, 0);
                acc[m][nf] = __builtin_amdgcn_mfma_f32_16x16x32_bf16(cah[m], blv, acc[m][nf], 0, 0, 0);
            }
        }
        #pragma unroll
        for (int m = 0; m < 4; ++m) cah[m] = nah[m];
    }

    // epilogue: D row=(l>>4)*4+r -> co, col=l&15 -> sp; hi plane only
    const int rr = (l >> 4) * 4, cc = l & 15;
    #pragma unroll
    for (int m = 0; m < 4; ++m) {
        const int cb = co_w + 16 * m + rr;
        #pragma unroll
        for (int nf = 0; nf < 7; ++nf) {
            const int p = p0 + nf * 16 + cc;
            #pragma unroll
            for (int r = 0; r < 4; ++r)
                dh[(size_t)(cb + r) * SP + p] = bf_hi(acc[m][nf][r]);
        }
    }
}

// ---------------------------------------------------------------------------
// gemm_a_mfma v7: 1-pass bf16 (H_hi·N_hi). LDS 16 KB (Ah/Bh).
// Staging: 16 one-KB units over 4 waves (4 GLOAD_LDS per wave).
// ---------------------------------------------------------------------------
__global__ __launch_bounds__(256, 2)
void gemm_a_mfma(const ushort* __restrict__ h1h, const ushort* __restrict__ hnh,
                 float* __restrict__ attn)
{
    __shared__ __align__(16) ushort Ah[64][64];
    __shared__ __align__(16) ushort Bh[64][64];
    const int tid = threadIdx.x;
    const int w = tid >> 6, l = tid & 63;
    const int wn = w >> 1, wm = w & 1;              // wave grid 2n x 2m
    const int img = blockIdx.x, tile = blockIdx.y;
    const int n0 = (tile & 3) * 64, m0 = (tile >> 2) * 64;

    const ushort* __restrict__ mat0 = h1h + ((size_t)img * COUT + n0) * SP;
    const ushort* __restrict__ mat1 = hnh + ((size_t)img * COUT + m0) * SP;

    f32x4 acc[2][2];
    #pragma unroll
    for (int i = 0; i < 2; ++i)
        #pragma unroll
        for (int j = 0; j < 2; ++j) acc[i][j] = (f32x4){0.f, 0.f, 0.f, 0.f};

    // staging: 16 units (mat u>>3, seg u&7); wave w -> units 4w..4w+3.
    const int lr = l >> 3, gp = l & 7;               // lane row-in-seg, phys grp
    const int glog = gp ^ lr;                        // swizzled source group
    const ushort* gptr[4];
    ushort* lptr[4];
    #pragma unroll
    for (int t = 0; t < 4; ++t) {
        const int u = 4 * w + t, mat = u >> 3, seg = u & 7;
        const ushort* ms = (mat == 0) ? mat0 : mat1;
        ushort* lb = (mat == 0) ? &Ah[0][0] : &Bh[0][0];
        gptr[t] = ms + (size_t)(seg * 8 + lr) * SP + glog * 8;
        lptr[t] = lb + seg * 8 * 64;                 // wave-uniform base
    }

    for (int k0 = 0; k0 < SP; k0 += 64) {
        #pragma unroll
        for (int t = 0; t < 4; ++t)
            GLOAD_LDS(gptr[t] + k0, lptr[t]);
        __syncthreads();                             // drains vmcnt before barrier

        #pragma unroll
        for (int ks = 0; ks < 2; ++ks) {
            const int grp = ks * 4 + (l >> 4);
            short8v ahf[2], bhf[2];
            #pragma unroll
            for (int i = 0; i < 2; ++i) {
                const int ar_ = 32 * wn + 16 * i + (l & 15);
                ahf[i] = *(const short8v*)&Ah[ar_][SWZ(ar_, grp)];
                const int br_ = 32 * wm + 16 * i + (l & 15);
                bhf[i] = *(const short8v*)&Bh[br_][SWZ(br_, grp)];
            }
            #pragma unroll
            for (int i = 0; i < 2; ++i)
                #pragma unroll
                for (int j = 0; j < 2; ++j)
                    acc[i][j] = __builtin_amdgcn_mfma_f32_16x16x32_bf16(ahf[i], bhf[j], acc[i][j], 0, 0, 0);
        }
        __syncthreads();
    }

    const int rr = (l >> 4) * 4, cc = l & 15;
    float* __restrict__ aimg = attn + (size_t)img * COUT * COUT;
    #pragma unroll
    for (int i = 0; i < 2; ++i) {
        const int nb = n0 + 32 * wn + 16 * i + rr;
        #pragma unroll
        for (int j = 0; j < 2; ++j) {
            const int m = m0 + 32 * wm + 16 * j + cc;
            #pragma unroll
            for (int r = 0; r < 4; ++r) {
                float v = acc[i][j][r];
                v = (v >= 0.f) ? v : NEG_SLOPE * v;
                aimg[(size_t)(nb + r) * COUT + m] = v;
            }
        }
    }
}

// ---------------------------------------------------------------------------
// softmax over axis n (dim=1) per (b,m) column, in place. (unchanged)
// ---------------------------------------------------------------------------
__global__ __launch_bounds__(64)
void softmax_k(float* __restrict__ attn)
{
    const int b = blockIdx.y;
    const int m = blockIdx.x * 64 + threadIdx.x;
    float* a = attn + (size_t)b * COUT * COUT;
    float mx = -1e30f;
    for (int n_ = 0; n_ < COUT; ++n_) mx = fmaxf(mx, a[n_ * COUT + m]);
    float s = 0.f;
    for (int n_ = 0; n_ < COUT; ++n_) s += expf(a[n_ * COUT + m] - mx);
    float inv = 1.f / s;
    for (int n_ = 0; n_ < COUT; ++n_)
        a[n_ * COUT + m] = expf(a[n_ * COUT + m] - mx) * inv;
}

// ---------------------------------------------------------------------------
// gemm_agg_mfma v4: single-pass bf16 GEMM; blend now reads h1 hi plane only
// (|d| = 0.9 * bf16 rounding ~ 0.002 abs).
// ---------------------------------------------------------------------------
__global__ __launch_bounds__(256, 4)
void gemm_agg_mfma(const float* __restrict__ attn,
                   const ushort* __restrict__ h1h,
                   float* __restrict__ out)
{
    __shared__ __align__(16) ushort Ah[128][72];
    __shared__ __align__(16) ushort Bh[112][72];
    const int tid = threadIdx.x, w = tid >> 6, l = tid & 63;
    const int f0 = blockIdx.x * 112;
    const int n0 = blockIdx.y * 128;
    const int img = blockIdx.z;

    const float*  __restrict__ A  = attn + (size_t)img * COUT * COUT;
    const ushort* __restrict__ Hh = h1h + (size_t)img * COUT * SP;

    f32x4 acc[2][7];
    #pragma unroll
    for (int nf = 0; nf < 2; ++nf)
        #pragma unroll
        for (int mf = 0; mf < 7; ++mf) acc[nf][mf] = (f32x4){0.f, 0.f, 0.f, 0.f};

    const int ar = tid >> 1, ac = (tid & 1) * 32;    // A: 128 rows x 2 halves
    const int bm = tid >> 2, bq = tid & 3, bfo = bq * 28;  // B: 64 rows x 4 quarters

    for (int k0 = 0; k0 < COUT; k0 += 64) {
        {   // A: attn[n0+ar][k0+ac..+31] f32 -> bf16 hi -> Ah (packed b32)
            const float* g = A + (size_t)(n0 + ar) * COUT + k0 + ac;
            uint* dh = (uint*)&Ah[ar][ac];
            #pragma unroll
            for (int q = 0; q < 8; ++q) {
                float4 v = *(const float4*)(g + 4 * q);
                dh[2 * q]     = (uint)bf_hi(v.x) | ((uint)bf_hi(v.y) << 16);
                dh[2 * q + 1] = (uint)bf_hi(v.z) | ((uint)bf_hi(v.w) << 16);
            }
        }
        {   // B: Hh[k0+bm][f0+bfo..+27] -> transpose -> Bh[f][bm] (all 256 thr)
            const ushort* g = Hh + (size_t)(k0 + bm) * SP + f0 + bfo;
            #pragma unroll
            for (int e = 0; e < 7; ++e) {
                uint2 v = *(const uint2*)(g + 4 * e);
                const ushort* vp = (const ushort*)&v;
                #pragma unroll
                for (int j = 0; j < 4; ++j)
                    Bh[bfo + 4 * e + j][bm] = vp[j];
            }
        }
        __syncthreads();
        #pragma unroll
        for (int ks = 0; ks < 2; ++ks) {
            const int kb = ks * 32 + (l >> 4) * 8;
            short8v ah[2];
            #pragma unroll
            for (int nf = 0; nf < 2; ++nf) {
                const int row = 32 * w + 16 * nf + (l & 15);
                ah[nf] = *(const short8v*)&Ah[row][kb];
            }
            #pragma unroll
            for (int mf = 0; mf < 7; ++mf) {
                const int br = mf * 16 + (l & 15);
                short8v bh = *(const short8v*)&Bh[br][kb];
                #pragma unroll
                for (int nf = 0; nf < 2; ++nf)
                    acc[nf][mf] = __builtin_amdgcn_mfma_f32_16x16x32_bf16(ah[nf], bh, acc[nf][mf], 0, 0, 0);
            }
        }
        __syncthreads();
    }

    const int rr = (l >> 4) * 4, cc = l & 15;
    float* __restrict__ orow = out + (size_t)img * COUT * SP;
    #pragma unroll
    for (int nf = 0; nf < 2; ++nf) {
        const int nb = n0 + 32 * w + 16 * nf + rr;
        #pragma unroll
        for (int mf = 0; mf < 7; ++mf) {
            const int f = f0 + 16 * mf + cc;
            #pragma unroll
            for (int r = 0; r < 4; ++r) {
                const int n = nb + r;
                float h = bfr(Hh[(size_t)n * SP + f]);
                orow[(size_t)n * SP + f] = 0.1f * acc[nf][mf][r] + 0.9f * h;
            }
        }
    }
}

// ---------------------------------------------------------------------------
extern "C" void kernel_launch(void* const* d_in, const int* in_sizes, int n_in,
                              void* d_out, int out_size, void* d_ws, size_t ws_size,
                              hipStream_t stream)
{
    const float* x    = (const float*)d_in[0];
    const float* nn   = (const float*)d_in[1];
    const float* W    = (const float*)d_in[2];
    const float* bias = (const float*)d_in[3];
    float* out = (float*)d_out;

    // ws: h1b_hi (51.4 MB) | zone: conv phase Wf_hi (0.59 MB);
    //     gemm phase attn f32 (8.39 MB, overlaps dead Wf).
    ushort* h1b_hi = (ushort*)d_ws;
    char*   zone   = (char*)(h1b_hi + (size_t)NB * COUT * SP);
    ushort* Wf_hi  = (ushort*)zone;
    float*  attn   = (float*)zone;          // overwrites Wf after convs complete
    // d_out (102.8 MB): hnb_hi (51.4) until gemm_agg_mfma overwrites with out f32.
    ushort* hnb_hi = (ushort*)d_out;

    pack_w    <<<576, 256, 0, stream>>>(W, Wf_hi);
    conv_fused<<<dim3(28, 2 * NB), 256, 0, stream>>>(x, nn, Wf_hi, bias,
                                                     h1b_hi, hnb_hi);
    gemm_a_mfma  <<<dim3(32, 16),    256, 0, stream>>>(h1b_hi, hnb_hi, attn);
    softmax_k    <<<dim3(4, NB),     64,  0, stream>>>(attn);
    gemm_agg_mfma<<<dim3(28, 2, NB), 256, 0, stream>>>(attn, h1b_hi, out);
}

// Round 24
// 252.817 us; speedup vs baseline: 1.4719x; 1.1220x over previous
//
#include <hip/hip_runtime.h>
#include <hip/hip_bf16.h>
#include <cstddef>

#define SP 3136          // 56*56
#define CIN 64
#define COUT 256
#define NB 32
#define NEG_SLOPE 0.01f

typedef __attribute__((ext_vector_type(8))) short short8v;  // 8 bf16 (4 VGPRs)
typedef __attribute__((ext_vector_type(4))) float f32x4;    // MFMA accumulator

__device__ __forceinline__ float bfr(ushort h) {
    union { uint u; float f; } c; c.u = ((uint)h) << 16; return c.f;
}
__device__ __forceinline__ ushort bf_hi(float v) {
    __hip_bfloat16 h = __float2bfloat16(v);
    return *(ushort*)&h;
}

// XOR swizzle: logical 8-ushort group g of row -> physical ushort offset
#define SWZ(row, g) ((((g) ^ ((row) & 7))) * 8)

// direct global->LDS DMA, 16B per lane (dest = wave-uniform base + lane*16)
#define GLOAD_LDS(gp, lp) __builtin_amdgcn_global_load_lds(                    \
    (const __attribute__((address_space(1))) void*)(gp),                       \
    (__attribute__((address_space(3))) void*)(lp), 16, 0, 0)

// ---------------------------------------------------------------------------
// pack_w: W[co][ci][ky][kx] f32 -> fragment-contiguous hi plane
// ---------------------------------------------------------------------------
__global__ __launch_bounds__(256)
void pack_w(const float* __restrict__ W, ushort* __restrict__ wh)
{
    const int id = blockIdx.x * 256 + threadIdx.x;   // 147456 = 9*256*64
    const int ci = id & 63, co = (id >> 6) & 255, tap = id >> 14;
    float v = W[(size_t)(co * 64 + ci) * 9 + tap];
    const int ks = ci >> 5, cig = (ci >> 3) & 3, ce = ci & 7;
    const size_t o = (((size_t)(tap * 2 + ks) * 4 + cig) * 256 + co) * 8 + ce;
    wh[o] = bf_hi(v);
}

// ---------------------------------------------------------------------------
// conv_fused v8: PURE 1-pass bf16 MFMA conv (r24: drop B_lo — stored output is
// bf16 anyway, so compute-beyond-storage precision was wasted; dh1 0.0028 ->
// 0.0035 RSS). Bl plane gone: LDS 29.7 KB, staging stores hi only, 28 MFMA/it.
// ---------------------------------------------------------------------------
__global__ __launch_bounds__(256, 2)
void conv_fused(const float* __restrict__ xsrc, const float* __restrict__ nsrc,
                const ushort* __restrict__ Wf_hi,
                const float* __restrict__ bias,
                ushort* __restrict__ h1h, ushort* __restrict__ hnh)
{
    __shared__ __align__(16) ushort Bh[4 * 58 * 64]; // 29 KB
    const int tid = threadIdx.x;
    const int w = tid >> 6, l = tid & 63;
    const int rp  = blockIdx.x;                      // 0..27
    const int img = blockIdx.y;                      // 0..63
    const int imgb = img & (NB - 1);
    const int y0 = rp * 2, p0 = rp * 112;
    const int co_w = w * 64;                         // wave's co base (4x64=256)
    const bool isX = (img < NB);

    const float* __restrict__ src = (isX ? xsrc : nsrc) + (size_t)imgb * CIN * SP;
    ushort* __restrict__ dh = (isX ? h1h : hnh) + (size_t)imgb * COUT * SP;

    int sy[4];
    #pragma unroll
    for (int j = 0; j < 4; ++j) sy[j] = (y0 + 55 + j) % 56;   // padded row y0+j

    // ---- stage B once: raw f32 -> bf16 hi -> LDS [j][x][ci] swizzled ----
    {
        const int ci = tid >> 2, seg = tid & 3;      // 64 ci x 4 col-segments(14)
        #pragma unroll
        for (int j = 0; j < 4; ++j) {
            const float* r = src + (size_t)ci * SP + sy[j] * 56 + seg * 14;
            #pragma unroll
            for (int c = 0; c < 14; ++c) {
                const int x = seg * 14 + c + 1;      // padded col = orig col + 1
                const int idx = ((j * 58 + x) << 6) + (((ci >> 3) ^ (x & 7)) << 3) + (ci & 7);
                Bh[idx] = bf_hi(r[c]);
            }
        }
        // wrap columns: x=0 <- orig col 55, x=57 <- orig col 0 (512 slots, 2/thr)
        #pragma unroll
        for (int s = 0; s < 2; ++s) {
            const int slot = tid * 2 + s;
            const int j2 = slot >> 7, ci2 = (slot >> 1) & 63, side = slot & 1;
            const float* r2 = src + (size_t)ci2 * SP + sy[j2] * 56;
            const float v = side ? r2[0] : r2[55];
            const int x = side ? 57 : 0;
            const int idx = ((j2 * 58 + x) << 6) + (((ci2 >> 3) ^ (x & 7)) << 3) + (ci2 & 7);
            Bh[idx] = bf_hi(v);
        }
    }
    __syncthreads();                                 // the ONLY barrier

    f32x4 acc[4][7];
    {
        const int rr = (l >> 4) * 4;
        #pragma unroll
        for (int m = 0; m < 4; ++m) {
            const int cb = co_w + 16 * m + rr;
            f32x4 bv = { bias[cb], bias[cb + 1], bias[cb + 2], bias[cb + 3] };
            #pragma unroll
            for (int nf = 0; nf < 7; ++nf) acc[m][nf] = bv;
        }
    }

    // per-nf spatial decomposition (lane-dependent, tap-invariant)
    int b58[7], bx[7];
    #pragma unroll
    for (int nf = 0; nf < 7; ++nf) {
        const int sp = nf * 16 + (l & 15);           // 0..111
        const int ry = (sp >= 56) ? 1 : 0;
        const int xx = sp - ry * 56;
        b58[nf] = ry * 58 + xx;
        bx[nf]  = xx;
    }

    // A-fragment base offsets (iter stride = 4*256*8 = 8192 ushorts)
    size_t aoff[4];
    #pragma unroll
    for (int m = 0; m < 4; ++m)
        aoff[m] = ((size_t)(l >> 4) * 256 + co_w + 16 * m + (l & 15)) * 8;

    short8v cah[4];                                  // current A fragments (hi only)
    #pragma unroll
    for (int m = 0; m < 4; ++m)
        cah[m] = *(const short8v*)(Wf_hi + aoff[m]);

    for (int it = 0; it < 18; ++it) {                // it = tap*2 + ks
        const int tap = it >> 1, ks = it & 1;
        const int dy = tap / 3, dx = tap - dy * 3;
        const int toff = dy * 58 + dx;
        const int grp = ks * 4 + (l >> 4);

        short8v nah[4];                              // prefetch next iter's A
        {
            const size_t po = (size_t)(it < 17 ? it + 1 : it) * 8192;
            #pragma unroll
            for (int m = 0; m < 4; ++m)
                nah[m] = *(const short8v*)(Wf_hi + aoff[m] + po);
        }

        #pragma unroll
        for (int nf = 0; nf < 7; ++nf) {
            const int x  = bx[nf] + dx;
            const int bi = ((b58[nf] + toff) << 6) + ((grp ^ (x & 7)) << 3);
            short8v bh = *(const short8v*)&Bh[bi];
            #pragma unroll
            for (int m = 0; m < 4; ++m)
                acc[m][nf] = __builtin_amdgcn_mfma_f32_16x16x32_bf16(cah[m], bh, acc[m][nf], 0, 0, 0);
        }
        #pragma unroll
        for (int m = 0; m < 4; ++m) cah[m] = nah[m];
    }

    // epilogue: D row=(l>>4)*4+r -> co, col=l&15 -> sp; hi plane only
    const int rr = (l >> 4) * 4, cc = l & 15;
    #pragma unroll
    for (int m = 0; m < 4; ++m) {
        const int cb = co_w + 16 * m + rr;
        #pragma unroll
        for (int nf = 0; nf < 7; ++nf) {
            const int p = p0 + nf * 16 + cc;
            #pragma unroll
            for (int r = 0; r < 4; ++r)
                dh[(size_t)(cb + r) * SP + p] = bf_hi(acc[m][nf][r]);
        }
    }
}

// ---------------------------------------------------------------------------
// gemm_a_mfma v7 (unchanged — 1-pass bf16, global_load_lds DMA staging)
// ---------------------------------------------------------------------------
__global__ __launch_bounds__(256, 2)
void gemm_a_mfma(const ushort* __restrict__ h1h, const ushort* __restrict__ hnh,
                 float* __restrict__ attn)
{
    __shared__ __align__(16) ushort Ah[64][64];
    __shared__ __align__(16) ushort Bh[64][64];
    const int tid = threadIdx.x;
    const int w = tid >> 6, l = tid & 63;
    const int wn = w >> 1, wm = w & 1;              // wave grid 2n x 2m
    const int img = blockIdx.x, tile = blockIdx.y;
    const int n0 = (tile & 3) * 64, m0 = (tile >> 2) * 64;

    const ushort* __restrict__ mat0 = h1h + ((size_t)img * COUT + n0) * SP;
    const ushort* __restrict__ mat1 = hnh + ((size_t)img * COUT + m0) * SP;

    f32x4 acc[2][2];
    #pragma unroll
    for (int i = 0; i < 2; ++i)
        #pragma unroll
        for (int j = 0; j < 2; ++j) acc[i][j] = (f32x4){0.f, 0.f, 0.f, 0.f};

    // staging: 16 units (mat u>>3, seg u&7); wave w -> units 4w..4w+3.
    const int lr = l >> 3, gp = l & 7;               // lane row-in-seg, phys grp
    const int glog = gp ^ lr;                        // swizzled source group
    const ushort* gptr[4];
    ushort* lptr[4];
    #pragma unroll
    for (int t = 0; t < 4; ++t) {
        const int u = 4 * w + t, mat = u >> 3, seg = u & 7;
        const ushort* ms = (mat == 0) ? mat0 : mat1;
        ushort* lb = (mat == 0) ? &Ah[0][0] : &Bh[0][0];
        gptr[t] = ms + (size_t)(seg * 8 + lr) * SP + glog * 8;
        lptr[t] = lb + seg * 8 * 64;                 // wave-uniform base
    }

    for (int k0 = 0; k0 < SP; k0 += 64) {
        #pragma unroll
        for (int t = 0; t < 4; ++t)
            GLOAD_LDS(gptr[t] + k0, lptr[t]);
        __syncthreads();                             // drains vmcnt before barrier

        #pragma unroll
        for (int ks = 0; ks < 2; ++ks) {
            const int grp = ks * 4 + (l >> 4);
            short8v ahf[2], bhf[2];
            #pragma unroll
            for (int i = 0; i < 2; ++i) {
                const int ar_ = 32 * wn + 16 * i + (l & 15);
                ahf[i] = *(const short8v*)&Ah[ar_][SWZ(ar_, grp)];
                const int br_ = 32 * wm + 16 * i + (l & 15);
                bhf[i] = *(const short8v*)&Bh[br_][SWZ(br_, grp)];
            }
            #pragma unroll
            for (int i = 0; i < 2; ++i)
                #pragma unroll
                for (int j = 0; j < 2; ++j)
                    acc[i][j] = __builtin_amdgcn_mfma_f32_16x16x32_bf16(ahf[i], bhf[j], acc[i][j], 0, 0, 0);
        }
        __syncthreads();
    }

    const int rr = (l >> 4) * 4, cc = l & 15;
    float* __restrict__ aimg = attn + (size_t)img * COUT * COUT;
    #pragma unroll
    for (int i = 0; i < 2; ++i) {
        const int nb = n0 + 32 * wn + 16 * i + rr;
        #pragma unroll
        for (int j = 0; j < 2; ++j) {
            const int m = m0 + 32 * wm + 16 * j + cc;
            #pragma unroll
            for (int r = 0; r < 4; ++r) {
                float v = acc[i][j][r];
                v = (v >= 0.f) ? v : NEG_SLOPE * v;
                aimg[(size_t)(nb + r) * COUT + m] = v;
            }
        }
    }
}

// ---------------------------------------------------------------------------
// softmax over axis n (dim=1) per (b,m) column, in place. (unchanged)
// ---------------------------------------------------------------------------
__global__ __launch_bounds__(64)
void softmax_k(float* __restrict__ attn)
{
    const int b = blockIdx.y;
    const int m = blockIdx.x * 64 + threadIdx.x;
    float* a = attn + (size_t)b * COUT * COUT;
    float mx = -1e30f;
    for (int n_ = 0; n_ < COUT; ++n_) mx = fmaxf(mx, a[n_ * COUT + m]);
    float s = 0.f;
    for (int n_ = 0; n_ < COUT; ++n_) s += expf(a[n_ * COUT + m] - mx);
    float inv = 1.f / s;
    for (int n_ = 0; n_ < COUT; ++n_)
        a[n_ * COUT + m] = expf(a[n_ * COUT + m] - mx) * inv;
}

// ---------------------------------------------------------------------------
// gemm_agg_mfma v4 (unchanged — single-pass bf16, hi-plane blend)
// ---------------------------------------------------------------------------
__global__ __launch_bounds__(256, 4)
void gemm_agg_mfma(const float* __restrict__ attn,
                   const ushort* __restrict__ h1h,
                   float* __restrict__ out)
{
    __shared__ __align__(16) ushort Ah[128][72];
    __shared__ __align__(16) ushort Bh[112][72];
    const int tid = threadIdx.x, w = tid >> 6, l = tid & 63;
    const int f0 = blockIdx.x * 112;
    const int n0 = blockIdx.y * 128;
    const int img = blockIdx.z;

    const float*  __restrict__ A  = attn + (size_t)img * COUT * COUT;
    const ushort* __restrict__ Hh = h1h + (size_t)img * COUT * SP;

    f32x4 acc[2][7];
    #pragma unroll
    for (int nf = 0; nf < 2; ++nf)
        #pragma unroll
        for (int mf = 0; mf < 7; ++mf) acc[nf][mf] = (f32x4){0.f, 0.f, 0.f, 0.f};

    const int ar = tid >> 1, ac = (tid & 1) * 32;    // A: 128 rows x 2 halves
    const int bm = tid >> 2, bq = tid & 3, bfo = bq * 28;  // B: 64 rows x 4 quarters

    for (int k0 = 0; k0 < COUT; k0 += 64) {
        {   // A: attn[n0+ar][k0+ac..+31] f32 -> bf16 hi -> Ah (packed b32)
            const float* g = A + (size_t)(n0 + ar) * COUT + k0 + ac;
            uint* dh = (uint*)&Ah[ar][ac];
            #pragma unroll
            for (int q = 0; q < 8; ++q) {
                float4 v = *(const float4*)(g + 4 * q);
                dh[2 * q]     = (uint)bf_hi(v.x) | ((uint)bf_hi(v.y) << 16);
                dh[2 * q + 1] = (uint)bf_hi(v.z) | ((uint)bf_hi(v.w) << 16);
            }
        }
        {   // B: Hh[k0+bm][f0+bfo..+27] -> transpose -> Bh[f][bm] (all 256 thr)
            const ushort* g = Hh + (size_t)(k0 + bm) * SP + f0 + bfo;
            #pragma unroll
            for (int e = 0; e < 7; ++e) {
                uint2 v = *(const uint2*)(g + 4 * e);
                const ushort* vp = (const ushort*)&v;
                #pragma unroll
                for (int j = 0; j < 4; ++j)
                    Bh[bfo + 4 * e + j][bm] = vp[j];
            }
        }
        __syncthreads();
        #pragma unroll
        for (int ks = 0; ks < 2; ++ks) {
            const int kb = ks * 32 + (l >> 4) * 8;
            short8v ah[2];
            #pragma unroll
            for (int nf = 0; nf < 2; ++nf) {
                const int row = 32 * w + 16 * nf + (l & 15);
                ah[nf] = *(const short8v*)&Ah[row][kb];
            }
            #pragma unroll
            for (int mf = 0; mf < 7; ++mf) {
                const int br = mf * 16 + (l & 15);
                short8v bh = *(const short8v*)&Bh[br][kb];
                #pragma unroll
                for (int nf = 0; nf < 2; ++nf)
                    acc[nf][mf] = __builtin_amdgcn_mfma_f32_16x16x32_bf16(ah[nf], bh, acc[nf][mf], 0, 0, 0);
            }
        }
        __syncthreads();
    }

    const int rr = (l >> 4) * 4, cc = l & 15;
    float* __restrict__ orow = out + (size_t)img * COUT * SP;
    #pragma unroll
    for (int nf = 0; nf < 2; ++nf) {
        const int nb = n0 + 32 * w + 16 * nf + rr;
        #pragma unroll
        for (int mf = 0; mf < 7; ++mf) {
            const int f = f0 + 16 * mf + cc;
            #pragma unroll
            for (int r = 0; r < 4; ++r) {
                const int n = nb + r;
                float h = bfr(Hh[(size_t)n * SP + f]);
                orow[(size_t)n * SP + f] = 0.1f * acc[nf][mf][r] + 0.9f * h;
            }
        }
    }
}

// ---------------------------------------------------------------------------
extern "C" void kernel_launch(void* const* d_in, const int* in_sizes, int n_in,
                              void* d_out, int out_size, void* d_ws, size_t ws_size,
                              hipStream_t stream)
{
    const float* x    = (const float*)d_in[0];
    const float* nn   = (const float*)d_in[1];
    const float* W    = (const float*)d_in[2];
    const float* bias = (const float*)d_in[3];
    float* out = (float*)d_out;

    // ws: h1b_hi (51.4 MB) | zone: conv phase Wf_hi (0.59 MB);
    //     gemm phase attn f32 (8.39 MB, overlaps dead Wf).
    ushort* h1b_hi = (ushort*)d_ws;
    char*   zone   = (char*)(h1b_hi + (size_t)NB * COUT * SP);
    ushort* Wf_hi  = (ushort*)zone;
    float*  attn   = (float*)zone;          // overwrites Wf after convs complete
    // d_out (102.8 MB): hnb_hi (51.4) until gemm_agg_mfma overwrites with out f32.
    ushort* hnb_hi = (ushort*)d_out;

    pack_w    <<<576, 256, 0, stream>>>(W, Wf_hi);
    conv_fused<<<dim3(28, 2 * NB), 256, 0, stream>>>(x, nn, Wf_hi, bias,
                                                     h1b_hi, hnb_hi);
    gemm_a_mfma  <<<dim3(32, 16),    256, 0, stream>>>(h1b_hi, hnb_hi, attn);
    softmax_k    <<<dim3(4, NB),     64,  0, stream>>>(attn);
    gemm_agg_mfma<<<dim3(28, 2, NB), 256, 0, stream>>>(attn, h1b_hi, out);
}

// Round 25
// 245.205 us; speedup vs baseline: 1.5176x; 1.0310x over previous
//
#include <hip/hip_runtime.h>
#include <hip/hip_bf16.h>
#include <cstddef>

#define SP 3136          // 56*56
#define CIN 64
#define COUT 256
#define NB 32
#define NEG_SLOPE 0.01f

typedef __attribute__((ext_vector_type(8))) short short8v;  // 8 bf16 (4 VGPRs)
typedef __attribute__((ext_vector_type(4))) float f32x4;    // MFMA accumulator

__device__ __forceinline__ float bfr(ushort h) {
    union { uint u; float f; } c; c.u = ((uint)h) << 16; return c.f;
}
__device__ __forceinline__ ushort bf_hi(float v) {
    __hip_bfloat16 h = __float2bfloat16(v);
    return *(ushort*)&h;
}

// XOR swizzle: logical 8-ushort group g of row -> physical ushort offset
#define SWZ(row, g) ((((g) ^ ((row) & 7))) * 8)

// direct global->LDS DMA, 16B per lane (dest = wave-uniform base + lane*16)
#define GLOAD_LDS(gp, lp) __builtin_amdgcn_global_load_lds(                    \
    (const __attribute__((address_space(1))) void*)(gp),                       \
    (__attribute__((address_space(3))) void*)(lp), 16, 0, 0)

// ---------------------------------------------------------------------------
// pack_w: W[co][ci][ky][kx] f32 -> fragment-contiguous hi plane (unchanged)
// ---------------------------------------------------------------------------
__global__ __launch_bounds__(256)
void pack_w(const float* __restrict__ W, ushort* __restrict__ wh)
{
    const int id = blockIdx.x * 256 + threadIdx.x;   // 147456 = 9*256*64
    const int ci = id & 63, co = (id >> 6) & 255, tap = id >> 14;
    float v = W[(size_t)(co * 64 + ci) * 9 + tap];
    const int ks = ci >> 5, cig = (ci >> 3) & 3, ce = ci & 7;
    const size_t o = (((size_t)(tap * 2 + ks) * 4 + cig) * 256 + co) * 8 + ce;
    wh[o] = bf_hi(v);
}

// ---------------------------------------------------------------------------
// conv_fused v9: 1-pass bf16 MFMA conv (r24) + r25: XCD-locality block swizzle.
// 1D grid 1792: xcd = bid%8, rp = (bid/8)%28, img = xcd + 8*(bid/224).
// All 28 row-blocks of an image land on ONE XCD -> 0.8 MB input L2-resident,
// row-overlap reads become L2 hits (bijective remap, outputs bit-identical).
// ---------------------------------------------------------------------------
__global__ __launch_bounds__(256, 2)
void conv_fused(const float* __restrict__ xsrc, const float* __restrict__ nsrc,
                const ushort* __restrict__ Wf_hi,
                const float* __restrict__ bias,
                ushort* __restrict__ h1h, ushort* __restrict__ hnh)
{
    __shared__ __align__(16) ushort Bh[4 * 58 * 64]; // 29 KB
    const int tid = threadIdx.x;
    const int w = tid >> 6, l = tid & 63;
    const int bid = blockIdx.x;                      // 0..1791
    const int xcd = bid & 7, s = bid >> 3;           // s 0..223
    const int rp  = s % 28;                          // 0..27
    const int img = xcd + 8 * (s / 28);              // 0..63
    const int imgb = img & (NB - 1);
    const int y0 = rp * 2, p0 = rp * 112;
    const int co_w = w * 64;                         // wave's co base (4x64=256)
    const bool isX = (img < NB);

    const float* __restrict__ src = (isX ? xsrc : nsrc) + (size_t)imgb * CIN * SP;
    ushort* __restrict__ dh = (isX ? h1h : hnh) + (size_t)imgb * COUT * SP;

    int sy[4];
    #pragma unroll
    for (int j = 0; j < 4; ++j) sy[j] = (y0 + 55 + j) % 56;   // padded row y0+j

    // ---- stage B once: raw f32 -> bf16 hi -> LDS [j][x][ci] swizzled ----
    {
        const int ci = tid >> 2, seg = tid & 3;      // 64 ci x 4 col-segments(14)
        #pragma unroll
        for (int j = 0; j < 4; ++j) {
            const float* r = src + (size_t)ci * SP + sy[j] * 56 + seg * 14;
            #pragma unroll
            for (int c = 0; c < 14; ++c) {
                const int x = seg * 14 + c + 1;      // padded col = orig col + 1
                const int idx = ((j * 58 + x) << 6) + (((ci >> 3) ^ (x & 7)) << 3) + (ci & 7);
                Bh[idx] = bf_hi(r[c]);
            }
        }
        // wrap columns: x=0 <- orig col 55, x=57 <- orig col 0 (512 slots, 2/thr)
        #pragma unroll
        for (int s2 = 0; s2 < 2; ++s2) {
            const int slot = tid * 2 + s2;
            const int j2 = slot >> 7, ci2 = (slot >> 1) & 63, side = slot & 1;
            const float* r2 = src + (size_t)ci2 * SP + sy[j2] * 56;
            const float v = side ? r2[0] : r2[55];
            const int x = side ? 57 : 0;
            const int idx = ((j2 * 58 + x) << 6) + (((ci2 >> 3) ^ (x & 7)) << 3) + (ci2 & 7);
            Bh[idx] = bf_hi(v);
        }
    }
    __syncthreads();                                 // the ONLY barrier

    f32x4 acc[4][7];
    {
        const int rr = (l >> 4) * 4;
        #pragma unroll
        for (int m = 0; m < 4; ++m) {
            const int cb = co_w + 16 * m + rr;
            f32x4 bv = { bias[cb], bias[cb + 1], bias[cb + 2], bias[cb + 3] };
            #pragma unroll
            for (int nf = 0; nf < 7; ++nf) acc[m][nf] = bv;
        }
    }

    // per-nf spatial decomposition (lane-dependent, tap-invariant)
    int b58[7], bx[7];
    #pragma unroll
    for (int nf = 0; nf < 7; ++nf) {
        const int sp = nf * 16 + (l & 15);           // 0..111
        const int ry = (sp >= 56) ? 1 : 0;
        const int xx = sp - ry * 56;
        b58[nf] = ry * 58 + xx;
        bx[nf]  = xx;
    }

    // A-fragment base offsets (iter stride = 4*256*8 = 8192 ushorts)
    size_t aoff[4];
    #pragma unroll
    for (int m = 0; m < 4; ++m)
        aoff[m] = ((size_t)(l >> 4) * 256 + co_w + 16 * m + (l & 15)) * 8;

    short8v cah[4];                                  // current A fragments (hi only)
    #pragma unroll
    for (int m = 0; m < 4; ++m)
        cah[m] = *(const short8v*)(Wf_hi + aoff[m]);

    for (int it = 0; it < 18; ++it) {                // it = tap*2 + ks
        const int tap = it >> 1, ks = it & 1;
        const int dy = tap / 3, dx = tap - dy * 3;
        const int toff = dy * 58 + dx;
        const int grp = ks * 4 + (l >> 4);

        short8v nah[4];                              // prefetch next iter's A
        {
            const size_t po = (size_t)(it < 17 ? it + 1 : it) * 8192;
            #pragma unroll
            for (int m = 0; m < 4; ++m)
                nah[m] = *(const short8v*)(Wf_hi + aoff[m] + po);
        }

        #pragma unroll
        for (int nf = 0; nf < 7; ++nf) {
            const int x  = bx[nf] + dx;
            const int bi = ((b58[nf] + toff) << 6) + ((grp ^ (x & 7)) << 3);
            short8v bh = *(const short8v*)&Bh[bi];
            #pragma unroll
            for (int m = 0; m < 4; ++m)
                acc[m][nf] = __builtin_amdgcn_mfma_f32_16x16x32_bf16(cah[m], bh, acc[m][nf], 0, 0, 0);
        }
        #pragma unroll
        for (int m = 0; m < 4; ++m) cah[m] = nah[m];
    }

    // epilogue: D row=(l>>4)*4+r -> co, col=l&15 -> sp; hi plane only
    const int rr = (l >> 4) * 4, cc = l & 15;
    #pragma unroll
    for (int m = 0; m < 4; ++m) {
        const int cb = co_w + 16 * m + rr;
        #pragma unroll
        for (int nf = 0; nf < 7; ++nf) {
            const int p = p0 + nf * 16 + cc;
            #pragma unroll
            for (int r = 0; r < 4; ++r)
                dh[(size_t)(cb + r) * SP + p] = bf_hi(acc[m][nf][r]);
        }
    }
}

// ---------------------------------------------------------------------------
// gemm_a_mfma v8: 1-pass bf16 + r25 XCD-locality swizzle.
// 1D grid 512: xcd = bid%8, tile = (bid/8)%16, img = xcd + 8*(bid/128).
// All 16 tiles of an image on ONE XCD -> 3.2 MB A/B panels L2-resident.
// ---------------------------------------------------------------------------
__global__ __launch_bounds__(256, 2)
void gemm_a_mfma(const ushort* __restrict__ h1h, const ushort* __restrict__ hnh,
                 float* __restrict__ attn)
{
    __shared__ __align__(16) ushort Ah[64][64];
    __shared__ __align__(16) ushort Bh[64][64];
    const int tid = threadIdx.x;
    const int w = tid >> 6, l = tid & 63;
    const int wn = w >> 1, wm = w & 1;              // wave grid 2n x 2m
    const int bid = blockIdx.x;                      // 0..511
    const int xcd = bid & 7, s = bid >> 3;           // s 0..63
    const int tile = s % 16;
    const int img  = xcd + 8 * (s / 16);             // 0..31 (4 groups x 8)
    const int n0 = (tile & 3) * 64, m0 = (tile >> 2) * 64;

    const ushort* __restrict__ mat0 = h1h + ((size_t)img * COUT + n0) * SP;
    const ushort* __restrict__ mat1 = hnh + ((size_t)img * COUT + m0) * SP;

    f32x4 acc[2][2];
    #pragma unroll
    for (int i = 0; i < 2; ++i)
        #pragma unroll
        for (int j = 0; j < 2; ++j) acc[i][j] = (f32x4){0.f, 0.f, 0.f, 0.f};

    // staging: 16 units (mat u>>3, seg u&7); wave w -> units 4w..4w+3.
    const int lr = l >> 3, gp = l & 7;               // lane row-in-seg, phys grp
    const int glog = gp ^ lr;                        // swizzled source group
    const ushort* gptr[4];
    ushort* lptr[4];
    #pragma unroll
    for (int t = 0; t < 4; ++t) {
        const int u = 4 * w + t, mat = u >> 3, seg = u & 7;
        const ushort* ms = (mat == 0) ? mat0 : mat1;
        ushort* lb = (mat == 0) ? &Ah[0][0] : &Bh[0][0];
        gptr[t] = ms + (size_t)(seg * 8 + lr) * SP + glog * 8;
        lptr[t] = lb + seg * 8 * 64;                 // wave-uniform base
    }

    for (int k0 = 0; k0 < SP; k0 += 64) {
        #pragma unroll
        for (int t = 0; t < 4; ++t)
            GLOAD_LDS(gptr[t] + k0, lptr[t]);
        __syncthreads();                             // drains vmcnt before barrier

        #pragma unroll
        for (int ks = 0; ks < 2; ++ks) {
            const int grp = ks * 4 + (l >> 4);
            short8v ahf[2], bhf[2];
            #pragma unroll
            for (int i = 0; i < 2; ++i) {
                const int ar_ = 32 * wn + 16 * i + (l & 15);
                ahf[i] = *(const short8v*)&Ah[ar_][SWZ(ar_, grp)];
                const int br_ = 32 * wm + 16 * i + (l & 15);
                bhf[i] = *(const short8v*)&Bh[br_][SWZ(br_, grp)];
            }
            #pragma unroll
            for (int i = 0; i < 2; ++i)
                #pragma unroll
                for (int j = 0; j < 2; ++j)
                    acc[i][j] = __builtin_amdgcn_mfma_f32_16x16x32_bf16(ahf[i], bhf[j], acc[i][j], 0, 0, 0);
        }
        __syncthreads();
    }

    const int rr = (l >> 4) * 4, cc = l & 15;
    float* __restrict__ aimg = attn + (size_t)img * COUT * COUT;
    #pragma unroll
    for (int i = 0; i < 2; ++i) {
        const int nb = n0 + 32 * wn + 16 * i + rr;
        #pragma unroll
        for (int j = 0; j < 2; ++j) {
            const int m = m0 + 32 * wm + 16 * j + cc;
            #pragma unroll
            for (int r = 0; r < 4; ++r) {
                float v = acc[i][j][r];
                v = (v >= 0.f) ? v : NEG_SLOPE * v;
                aimg[(size_t)(nb + r) * COUT + m] = v;
            }
        }
    }
}

// ---------------------------------------------------------------------------
// softmax over axis n (dim=1) per (b,m) column, in place. (unchanged)
// ---------------------------------------------------------------------------
__global__ __launch_bounds__(64)
void softmax_k(float* __restrict__ attn)
{
    const int b = blockIdx.y;
    const int m = blockIdx.x * 64 + threadIdx.x;
    float* a = attn + (size_t)b * COUT * COUT;
    float mx = -1e30f;
    for (int n_ = 0; n_ < COUT; ++n_) mx = fmaxf(mx, a[n_ * COUT + m]);
    float s = 0.f;
    for (int n_ = 0; n_ < COUT; ++n_) s += expf(a[n_ * COUT + m] - mx);
    float inv = 1.f / s;
    for (int n_ = 0; n_ < COUT; ++n_)
        a[n_ * COUT + m] = expf(a[n_ * COUT + m] - mx) * inv;
}

// ---------------------------------------------------------------------------
// gemm_agg_mfma v4 (unchanged — single-pass bf16, hi-plane blend)
// ---------------------------------------------------------------------------
__global__ __launch_bounds__(256, 4)
void gemm_agg_mfma(const float* __restrict__ attn,
                   const ushort* __restrict__ h1h,
                   float* __restrict__ out)
{
    __shared__ __align__(16) ushort Ah[128][72];
    __shared__ __align__(16) ushort Bh[112][72];
    const int tid = threadIdx.x, w = tid >> 6, l = tid & 63;
    const int f0 = blockIdx.x * 112;
    const int n0 = blockIdx.y * 128;
    const int img = blockIdx.z;

    const float*  __restrict__ A  = attn + (size_t)img * COUT * COUT;
    const ushort* __restrict__ Hh = h1h + (size_t)img * COUT * SP;

    f32x4 acc[2][7];
    #pragma unroll
    for (int nf = 0; nf < 2; ++nf)
        #pragma unroll
        for (int mf = 0; mf < 7; ++mf) acc[nf][mf] = (f32x4){0.f, 0.f, 0.f, 0.f};

    const int ar = tid >> 1, ac = (tid & 1) * 32;    // A: 128 rows x 2 halves
    const int bm = tid >> 2, bq = tid & 3, bfo = bq * 28;  // B: 64 rows x 4 quarters

    for (int k0 = 0; k0 < COUT; k0 += 64) {
        {   // A: attn[n0+ar][k0+ac..+31] f32 -> bf16 hi -> Ah (packed b32)
            const float* g = A + (size_t)(n0 + ar) * COUT + k0 + ac;
            uint* dh = (uint*)&Ah[ar][ac];
            #pragma unroll
            for (int q = 0; q < 8; ++q) {
                float4 v = *(const float4*)(g + 4 * q);
                dh[2 * q]     = (uint)bf_hi(v.x) | ((uint)bf_hi(v.y) << 16);
                dh[2 * q + 1] = (uint)bf_hi(v.z) | ((uint)bf_hi(v.w) << 16);
            }
        }
        {   // B: Hh[k0+bm][f0+bfo..+27] -> transpose -> Bh[f][bm] (all 256 thr)
            const ushort* g = Hh + (size_t)(k0 + bm) * SP + f0 + bfo;
            #pragma unroll
            for (int e = 0; e < 7; ++e) {
                uint2 v = *(const uint2*)(g + 4 * e);
                const ushort* vp = (const ushort*)&v;
                #pragma unroll
                for (int j = 0; j < 4; ++j)
                    Bh[bfo + 4 * e + j][bm] = vp[j];
            }
        }
        __syncthreads();
        #pragma unroll
        for (int ks = 0; ks < 2; ++ks) {
            const int kb = ks * 32 + (l >> 4) * 8;
            short8v ah[2];
            #pragma unroll
            for (int nf = 0; nf < 2; ++nf) {
                const int row = 32 * w + 16 * nf + (l & 15);
                ah[nf] = *(const short8v*)&Ah[row][kb];
            }
            #pragma unroll
            for (int mf = 0; mf < 7; ++mf) {
                const int br = mf * 16 + (l & 15);
                short8v bh = *(const short8v*)&Bh[br][kb];
                #pragma unroll
                for (int nf = 0; nf < 2; ++nf)
                    acc[nf][mf] = __builtin_amdgcn_mfma_f32_16x16x32_bf16(ah[nf], bh, acc[nf][mf], 0, 0, 0);
            }
        }
        __syncthreads();
    }

    const int rr = (l >> 4) * 4, cc = l & 15;
    float* __restrict__ orow = out + (size_t)img * COUT * SP;
    #pragma unroll
    for (int nf = 0; nf < 2; ++nf) {
        const int nb = n0 + 32 * w + 16 * nf + rr;
        #pragma unroll
        for (int mf = 0; mf < 7; ++mf) {
            const int f = f0 + 16 * mf + cc;
            #pragma unroll
            for (int r = 0; r < 4; ++r) {
                const int n = nb + r;
                float h = bfr(Hh[(size_t)n * SP + f]);
                orow[(size_t)n * SP + f] = 0.1f * acc[nf][mf][r] + 0.9f * h;
            }
        }
    }
}

// ---------------------------------------------------------------------------
extern "C" void kernel_launch(void* const* d_in, const int* in_sizes, int n_in,
                              void* d_out, int out_size, void* d_ws, size_t ws_size,
                              hipStream_t stream)
{
    const float* x    = (const float*)d_in[0];
    const float* nn   = (const float*)d_in[1];
    const float* W    = (const float*)d_in[2];
    const float* bias = (const float*)d_in[3];
    float* out = (float*)d_out;

    // ws: h1b_hi (51.4 MB) | zone: conv phase Wf_hi (0.59 MB);
    //     gemm phase attn f32 (8.39 MB, overlaps dead Wf).
    ushort* h1b_hi = (ushort*)d_ws;
    char*   zone   = (char*)(h1b_hi + (size_t)NB * COUT * SP);
    ushort* Wf_hi  = (ushort*)zone;
    float*  attn   = (float*)zone;          // overwrites Wf after convs complete
    // d_out (102.8 MB): hnb_hi (51.4) until gemm_agg_mfma overwrites with out f32.
    ushort* hnb_hi = (ushort*)d_out;

    pack_w    <<<576, 256, 0, stream>>>(W, Wf_hi);
    conv_fused<<<1792, 256, 0, stream>>>(x, nn, Wf_hi, bias, h1b_hi, hnb_hi);
    gemm_a_mfma  <<<512, 256, 0, stream>>>(h1b_hi, hnb_hi, attn);
    softmax_k    <<<dim3(4, NB),     64,  0, stream>>>(attn);
    gemm_agg_mfma<<<dim3(28, 2, NB), 256, 0, stream>>>(attn, h1b_hi, out);
}

// Round 26
// 196.826 us; speedup vs baseline: 1.8906x; 1.2458x over previous
//
#include <hip/hip_runtime.h>
#include <hip/hip_bf16.h>
#include <cstddef>

#define SP 3136          // 56*56
#define CIN 64
#define COUT 256
#define NB 32
#define NEG_SLOPE 0.01f

typedef __attribute__((ext_vector_type(8))) short short8v;  // 8 bf16 (4 VGPRs)
typedef __attribute__((ext_vector_type(4))) float f32x4;    // MFMA accumulator

__device__ __forceinline__ float bfr(ushort h) {
    union { uint u; float f; } c; c.u = ((uint)h) << 16; return c.f;
}
__device__ __forceinline__ ushort bf_hi(float v) {
    __hip_bfloat16 h = __float2bfloat16(v);
    return *(ushort*)&h;
}

// XOR swizzle: logical 8-ushort group g of row -> physical ushort offset
#define SWZ(row, g) ((((g) ^ ((row) & 7))) * 8)

// direct global->LDS DMA, 16B per lane (dest = wave-uniform base + lane*16)
#define GLOAD_LDS(gp, lp) __builtin_amdgcn_global_load_lds(                    \
    (const __attribute__((address_space(1))) void*)(gp),                       \
    (__attribute__((address_space(3))) void*)(lp), 16, 0, 0)

// ---------------------------------------------------------------------------
// pack_w: W[co][ci][ky][kx] f32 -> fragment-contiguous hi plane (unchanged)
// ---------------------------------------------------------------------------
__global__ __launch_bounds__(256)
void pack_w(const float* __restrict__ W, ushort* __restrict__ wh)
{
    const int id = blockIdx.x * 256 + threadIdx.x;   // 147456 = 9*256*64
    const int ci = id & 63, co = (id >> 6) & 255, tap = id >> 14;
    float v = W[(size_t)(co * 64 + ci) * 9 + tap];
    const int ks = ci >> 5, cig = (ci >> 3) & 3, ce = ci & 7;
    const size_t o = (((size_t)(tap * 2 + ks) * 4 + cig) * 256 + co) * 8 + ce;
    wh[o] = bf_hi(v);
}

// ---------------------------------------------------------------------------
// conv_fused v9 (unchanged from round 25 — 1-pass bf16, XCD swizzle)
// ---------------------------------------------------------------------------
__global__ __launch_bounds__(256, 2)
void conv_fused(const float* __restrict__ xsrc, const float* __restrict__ nsrc,
                const ushort* __restrict__ Wf_hi,
                const float* __restrict__ bias,
                ushort* __restrict__ h1h, ushort* __restrict__ hnh)
{
    __shared__ __align__(16) ushort Bh[4 * 58 * 64]; // 29 KB
    const int tid = threadIdx.x;
    const int w = tid >> 6, l = tid & 63;
    const int bid = blockIdx.x;                      // 0..1791
    const int xcd = bid & 7, s = bid >> 3;           // s 0..223
    const int rp  = s % 28;                          // 0..27
    const int img = xcd + 8 * (s / 28);              // 0..63
    const int imgb = img & (NB - 1);
    const int y0 = rp * 2, p0 = rp * 112;
    const int co_w = w * 64;                         // wave's co base (4x64=256)
    const bool isX = (img < NB);

    const float* __restrict__ src = (isX ? xsrc : nsrc) + (size_t)imgb * CIN * SP;
    ushort* __restrict__ dh = (isX ? h1h : hnh) + (size_t)imgb * COUT * SP;

    int sy[4];
    #pragma unroll
    for (int j = 0; j < 4; ++j) sy[j] = (y0 + 55 + j) % 56;   // padded row y0+j

    // ---- stage B once: raw f32 -> bf16 hi -> LDS [j][x][ci] swizzled ----
    {
        const int ci = tid >> 2, seg = tid & 3;      // 64 ci x 4 col-segments(14)
        #pragma unroll
        for (int j = 0; j < 4; ++j) {
            const float* r = src + (size_t)ci * SP + sy[j] * 56 + seg * 14;
            #pragma unroll
            for (int c = 0; c < 14; ++c) {
                const int x = seg * 14 + c + 1;      // padded col = orig col + 1
                const int idx = ((j * 58 + x) << 6) + (((ci >> 3) ^ (x & 7)) << 3) + (ci & 7);
                Bh[idx] = bf_hi(r[c]);
            }
        }
        // wrap columns: x=0 <- orig col 55, x=57 <- orig col 0 (512 slots, 2/thr)
        #pragma unroll
        for (int s2 = 0; s2 < 2; ++s2) {
            const int slot = tid * 2 + s2;
            const int j2 = slot >> 7, ci2 = (slot >> 1) & 63, side = slot & 1;
            const float* r2 = src + (size_t)ci2 * SP + sy[j2] * 56;
            const float v = side ? r2[0] : r2[55];
            const int x = side ? 57 : 0;
            const int idx = ((j2 * 58 + x) << 6) + (((ci2 >> 3) ^ (x & 7)) << 3) + (ci2 & 7);
            Bh[idx] = bf_hi(v);
        }
    }
    __syncthreads();                                 // the ONLY barrier

    f32x4 acc[4][7];
    {
        const int rr = (l >> 4) * 4;
        #pragma unroll
        for (int m = 0; m < 4; ++m) {
            const int cb = co_w + 16 * m + rr;
            f32x4 bv = { bias[cb], bias[cb + 1], bias[cb + 2], bias[cb + 3] };
            #pragma unroll
            for (int nf = 0; nf < 7; ++nf) acc[m][nf] = bv;
        }
    }

    // per-nf spatial decomposition (lane-dependent, tap-invariant)
    int b58[7], bx[7];
    #pragma unroll
    for (int nf = 0; nf < 7; ++nf) {
        const int sp = nf * 16 + (l & 15);           // 0..111
        const int ry = (sp >= 56) ? 1 : 0;
        const int xx = sp - ry * 56;
        b58[nf] = ry * 58 + xx;
        bx[nf]  = xx;
    }

    // A-fragment base offsets (iter stride = 4*256*8 = 8192 ushorts)
    size_t aoff[4];
    #pragma unroll
    for (int m = 0; m < 4; ++m)
        aoff[m] = ((size_t)(l >> 4) * 256 + co_w + 16 * m + (l & 15)) * 8;

    short8v cah[4];                                  // current A fragments (hi only)
    #pragma unroll
    for (int m = 0; m < 4; ++m)
        cah[m] = *(const short8v*)(Wf_hi + aoff[m]);

    for (int it = 0; it < 18; ++it) {                // it = tap*2 + ks
        const int tap = it >> 1, ks = it & 1;
        const int dy = tap / 3, dx = tap - dy * 3;
        const int toff = dy * 58 + dx;
        const int grp = ks * 4 + (l >> 4);

        short8v nah[4];                              // prefetch next iter's A
        {
            const size_t po = (size_t)(it < 17 ? it + 1 : it) * 8192;
            #pragma unroll
            for (int m = 0; m < 4; ++m)
                nah[m] = *(const short8v*)(Wf_hi + aoff[m] + po);
        }

        #pragma unroll
        for (int nf = 0; nf < 7; ++nf) {
            const int x  = bx[nf] + dx;
            const int bi = ((b58[nf] + toff) << 6) + ((grp ^ (x & 7)) << 3);
            short8v bh = *(const short8v*)&Bh[bi];
            #pragma unroll
            for (int m = 0; m < 4; ++m)
                acc[m][nf] = __builtin_amdgcn_mfma_f32_16x16x32_bf16(cah[m], bh, acc[m][nf], 0, 0, 0);
        }
        #pragma unroll
        for (int m = 0; m < 4; ++m) cah[m] = nah[m];
    }

    // epilogue: D row=(l>>4)*4+r -> co, col=l&15 -> sp; hi plane only
    const int rr = (l >> 4) * 4, cc = l & 15;
    #pragma unroll
    for (int m = 0; m < 4; ++m) {
        const int cb = co_w + 16 * m + rr;
        #pragma unroll
        for (int nf = 0; nf < 7; ++nf) {
            const int p = p0 + nf * 16 + cc;
            #pragma unroll
            for (int r = 0; r < 4; ++r)
                dh[(size_t)(cb + r) * SP + p] = bf_hi(acc[m][nf][r]);
        }
    }
}

// ---------------------------------------------------------------------------
// gemm_a_mfma v8 (unchanged from round 25)
// ---------------------------------------------------------------------------
__global__ __launch_bounds__(256, 2)
void gemm_a_mfma(const ushort* __restrict__ h1h, const ushort* __restrict__ hnh,
                 float* __restrict__ attn)
{
    __shared__ __align__(16) ushort Ah[64][64];
    __shared__ __align__(16) ushort Bh[64][64];
    const int tid = threadIdx.x;
    const int w = tid >> 6, l = tid & 63;
    const int wn = w >> 1, wm = w & 1;              // wave grid 2n x 2m
    const int bid = blockIdx.x;                      // 0..511
    const int xcd = bid & 7, s = bid >> 3;           // s 0..63
    const int tile = s % 16;
    const int img  = xcd + 8 * (s / 16);             // 0..31 (4 groups x 8)
    const int n0 = (tile & 3) * 64, m0 = (tile >> 2) * 64;

    const ushort* __restrict__ mat0 = h1h + ((size_t)img * COUT + n0) * SP;
    const ushort* __restrict__ mat1 = hnh + ((size_t)img * COUT + m0) * SP;

    f32x4 acc[2][2];
    #pragma unroll
    for (int i = 0; i < 2; ++i)
        #pragma unroll
        for (int j = 0; j < 2; ++j) acc[i][j] = (f32x4){0.f, 0.f, 0.f, 0.f};

    // staging: 16 units (mat u>>3, seg u&7); wave w -> units 4w..4w+3.
    const int lr = l >> 3, gp = l & 7;               // lane row-in-seg, phys grp
    const int glog = gp ^ lr;                        // swizzled source group
    const ushort* gptr[4];
    ushort* lptr[4];
    #pragma unroll
    for (int t = 0; t < 4; ++t) {
        const int u = 4 * w + t, mat = u >> 3, seg = u & 7;
        const ushort* ms = (mat == 0) ? mat0 : mat1;
        ushort* lb = (mat == 0) ? &Ah[0][0] : &Bh[0][0];
        gptr[t] = ms + (size_t)(seg * 8 + lr) * SP + glog * 8;
        lptr[t] = lb + seg * 8 * 64;                 // wave-uniform base
    }

    for (int k0 = 0; k0 < SP; k0 += 64) {
        #pragma unroll
        for (int t = 0; t < 4; ++t)
            GLOAD_LDS(gptr[t] + k0, lptr[t]);
        __syncthreads();                             // drains vmcnt before barrier

        #pragma unroll
        for (int ks = 0; ks < 2; ++ks) {
            const int grp = ks * 4 + (l >> 4);
            short8v ahf[2], bhf[2];
            #pragma unroll
            for (int i = 0; i < 2; ++i) {
                const int ar_ = 32 * wn + 16 * i + (l & 15);
                ahf[i] = *(const short8v*)&Ah[ar_][SWZ(ar_, grp)];
                const int br_ = 32 * wm + 16 * i + (l & 15);
                bhf[i] = *(const short8v*)&Bh[br_][SWZ(br_, grp)];
            }
            #pragma unroll
            for (int i = 0; i < 2; ++i)
                #pragma unroll
                for (int j = 0; j < 2; ++j)
                    acc[i][j] = __builtin_amdgcn_mfma_f32_16x16x32_bf16(ahf[i], bhf[j], acc[i][j], 0, 0, 0);
        }
        __syncthreads();
    }

    const int rr = (l >> 4) * 4, cc = l & 15;
    float* __restrict__ aimg = attn + (size_t)img * COUT * COUT;
    #pragma unroll
    for (int i = 0; i < 2; ++i) {
        const int nb = n0 + 32 * wn + 16 * i + rr;
        #pragma unroll
        for (int j = 0; j < 2; ++j) {
            const int m = m0 + 32 * wm + 16 * j + cc;
            #pragma unroll
            for (int r = 0; r < 4; ++r) {
                float v = acc[i][j][r];
                v = (v >= 0.f) ? v : NEG_SLOPE * v;
                aimg[(size_t)(nb + r) * COUT + m] = v;
            }
        }
    }
}

// ---------------------------------------------------------------------------
// softmax_k v2: softmax over axis n per (b,m) column; writes bf16 plane
// (the same f32->bf16 rounding agg's A-staging previously applied per k-tile,
// now done once). attn f32 read-only.
// ---------------------------------------------------------------------------
__global__ __launch_bounds__(64)
void softmax_k(const float* __restrict__ attn, ushort* __restrict__ attnb)
{
    const int b = blockIdx.y;
    const int m = blockIdx.x * 64 + threadIdx.x;
    const float* a = attn + (size_t)b * COUT * COUT;
    ushort* ab = attnb + (size_t)b * COUT * COUT;
    float mx = -1e30f;
    for (int n_ = 0; n_ < COUT; ++n_) mx = fmaxf(mx, a[n_ * COUT + m]);
    float s = 0.f;
    for (int n_ = 0; n_ < COUT; ++n_) s += expf(a[n_ * COUT + m] - mx);
    float inv = 1.f / s;
    for (int n_ = 0; n_ < COUT; ++n_)
        ab[n_ * COUT + m] = bf_hi(expf(a[n_ * COUT + m] - mx) * inv);
}

// ---------------------------------------------------------------------------
// gemm_agg_mfma v5: A staged via GLOAD_LDS DMA from bf16 attnb (no VALU
// conversion); B-transpose stride 76 (4-way bank conflict -> 2-way same-dword:
// group offsets 28*76=1064 dwords = 8 mod 32 -> disjoint bank quarters);
// XCD-img 1D grid (56 blocks of an image share one XCD's L2).
// ---------------------------------------------------------------------------
__global__ __launch_bounds__(256, 4)
void gemm_agg_mfma(const ushort* __restrict__ attnb,
                   const ushort* __restrict__ h1h,
                   float* __restrict__ out)
{
    __shared__ __align__(16) ushort Ah[128][64];     // 16 KB, DMA linear+SWZ
    __shared__ __align__(16) ushort Bh[112][76];     // 16.6 KB, stride 76
    const int tid = threadIdx.x, w = tid >> 6, l = tid & 63;
    const int bid = blockIdx.x;                      // 0..1791
    const int xcd = bid & 7, s = bid >> 3;           // s 0..223
    const int local = s % 56;
    const int img  = xcd + 8 * (s / 56);             // 0..31
    const int f0 = (local % 28) * 112;
    const int n0 = (local / 28) * 128;

    const ushort* __restrict__ A  = attnb + (size_t)img * COUT * COUT;
    const ushort* __restrict__ Hh = h1h + (size_t)img * COUT * SP;

    f32x4 acc[2][7];
    #pragma unroll
    for (int nf = 0; nf < 2; ++nf)
        #pragma unroll
        for (int mf = 0; mf < 7; ++mf) acc[nf][mf] = (f32x4){0.f, 0.f, 0.f, 0.f};

    // A DMA staging: 16 units (8 rows each); wave w -> units 4w..4w+3.
    const int lr = l >> 3, gp = l & 7;
    const int glog = gp ^ lr;
    const ushort* agp[4];
    ushort* alp[4];
    #pragma unroll
    for (int t = 0; t < 4; ++t) {
        const int seg = 4 * w + t;
        agp[t] = A + (size_t)(n0 + seg * 8 + lr) * COUT + glog * 8;
        alp[t] = &Ah[0][0] + seg * 8 * 64;           // wave-uniform base
    }
    // B staging (all 256 thr): row k0+bm -> Bh[f][bm], f quarter bfo
    const int bm = tid >> 2, bq = tid & 3, bfo = bq * 28;

    for (int k0 = 0; k0 < COUT; k0 += 64) {
        #pragma unroll
        for (int t = 0; t < 4; ++t)
            GLOAD_LDS(agp[t] + k0, alp[t]);
        {
            const ushort* g = Hh + (size_t)(k0 + bm) * SP + f0 + bfo;
            #pragma unroll
            for (int e = 0; e < 7; ++e) {
                uint2 v = *(const uint2*)(g + 4 * e);
                const ushort* vp = (const ushort*)&v;
                #pragma unroll
                for (int j = 0; j < 4; ++j)
                    Bh[bfo + 4 * e + j][bm] = vp[j];
            }
        }
        __syncthreads();
        #pragma unroll
        for (int ks = 0; ks < 2; ++ks) {
            const int grp = ks * 4 + (l >> 4);
            const int kb = ks * 32 + (l >> 4) * 8;
            short8v ah[2];
            #pragma unroll
            for (int nf = 0; nf < 2; ++nf) {
                const int row = 32 * w + 16 * nf + (l & 15);
                ah[nf] = *(const short8v*)&Ah[row][SWZ(row, grp)];
            }
            #pragma unroll
            for (int mf = 0; mf < 7; ++mf) {
                const int br = mf * 16 + (l & 15);
                short8v bh = *(const short8v*)&Bh[br][kb];
                #pragma unroll
                for (int nf = 0; nf < 2; ++nf)
                    acc[nf][mf] = __builtin_amdgcn_mfma_f32_16x16x32_bf16(ah[nf], bh, acc[nf][mf], 0, 0, 0);
            }
        }
        __syncthreads();
    }

    const int rr = (l >> 4) * 4, cc = l & 15;
    float* __restrict__ orow = out + (size_t)img * COUT * SP;
    #pragma unroll
    for (int nf = 0; nf < 2; ++nf) {
        const int nb = n0 + 32 * w + 16 * nf + rr;
        #pragma unroll
        for (int mf = 0; mf < 7; ++mf) {
            const int f = f0 + 16 * mf + cc;
            #pragma unroll
            for (int r = 0; r < 4; ++r) {
                const int n = nb + r;
                float h = bfr(Hh[(size_t)n * SP + f]);
                orow[(size_t)n * SP + f] = 0.1f * acc[nf][mf][r] + 0.9f * h;
            }
        }
    }
}

// ---------------------------------------------------------------------------
extern "C" void kernel_launch(void* const* d_in, const int* in_sizes, int n_in,
                              void* d_out, int out_size, void* d_ws, size_t ws_size,
                              hipStream_t stream)
{
    const float* x    = (const float*)d_in[0];
    const float* nn   = (const float*)d_in[1];
    const float* W    = (const float*)d_in[2];
    const float* bias = (const float*)d_in[3];
    float* out = (float*)d_out;

    // ws: h1b_hi (51.4 MB) | zone: conv phase Wf_hi (0.59 MB);
    //     gemm phase attn f32 (8.39 MB, overlaps dead Wf) | attnb bf16 (4.2 MB).
    ushort* h1b_hi = (ushort*)d_ws;
    char*   zone   = (char*)(h1b_hi + (size_t)NB * COUT * SP);
    ushort* Wf_hi  = (ushort*)zone;
    float*  attn   = (float*)zone;          // overwrites Wf after convs complete
    ushort* attnb  = (ushort*)(zone + (size_t)NB * COUT * COUT * sizeof(float));
    // d_out (102.8 MB): hnb_hi (51.4) until gemm_agg_mfma overwrites with out f32.
    ushort* hnb_hi = (ushort*)d_out;

    pack_w    <<<576, 256, 0, stream>>>(W, Wf_hi);
    conv_fused<<<1792, 256, 0, stream>>>(x, nn, Wf_hi, bias, h1b_hi, hnb_hi);
    gemm_a_mfma  <<<512, 256, 0, stream>>>(h1b_hi, hnb_hi, attn);
    softmax_k    <<<dim3(4, NB), 64, 0, stream>>>(attn, attnb);
    gemm_agg_mfma<<<1792, 256, 0, stream>>>(attnb, h1b_hi, out);
}